// Round 4
// baseline (720.275 us; speedup 1.0000x reference)
//
#include <hip/hip_runtime.h>

// SelfAttn (SAGAN block): B=4, C=512, N=4096, C8=64
// out = gamma * (V @ softmax(Q K^T)^T) + x ; also outputs attention [B,N,N].
// All GEMMs via v_mfma_f32_16x16x32_bf16; fp32 accumulate.

#define BB 4
#define CC 512
#define NN 4096
#define C8V 64

typedef __bf16 bf16x8 __attribute__((ext_vector_type(8)));
typedef float f32x4 __attribute__((ext_vector_type(4)));
typedef float f32x4v __attribute__((ext_vector_type(4)));   // for nontemporal builtins
typedef unsigned short u16x8 __attribute__((ext_vector_type(8)));

#if __has_builtin(__builtin_amdgcn_exp2f)
#define EXP2(x) __builtin_amdgcn_exp2f(x)
#else
#define EXP2(x) exp2f(x)
#endif

#define MFMA16(a, b, c) __builtin_amdgcn_mfma_f32_16x16x32_bf16((a), (b), (c), 0, 0, 0)

__device__ __forceinline__ unsigned short f2b(float f) {
  union { float f; unsigned u; } x; x.f = f;
  unsigned u = x.u;
  u += 0x7fffu + ((u >> 16) & 1u);   // RNE round to bf16
  return (unsigned short)(u >> 16);
}

__device__ __forceinline__ bf16x8 ldb8(const unsigned short* p) {
  return *reinterpret_cast<const bf16x8*>(p);
}

__device__ __forceinline__ f32x4v ntl4(const float* p) {
  return __builtin_nontemporal_load(reinterpret_cast<const f32x4v*>(p));
}

// 8 fp32 -> bf16x8 (RNE via compiler cvt)
__device__ __forceinline__ bf16x8 cvt8(f32x4v f0, f32x4v f1) {
  bf16x8 r;
  r[0] = (__bf16)f0.x; r[1] = (__bf16)f0.y; r[2] = (__bf16)f0.z; r[3] = (__bf16)f0.w;
  r[4] = (__bf16)f1.x; r[5] = (__bf16)f1.y; r[6] = (__bf16)f1.z; r[7] = (__bf16)f1.w;
  return r;
}

// ---------------- weights fp32 -> bf16 ----------------
__global__ __launch_bounds__(256) void k_cvt_w(
    const float* __restrict__ wq, const float* __restrict__ wk, const float* __restrict__ wv,
    unsigned short* __restrict__ wqb, unsigned short* __restrict__ wkb, unsigned short* __restrict__ wvb) {
  int i = blockIdx.x * 256 + threadIdx.x;
  if (i < 32768)        wqb[i] = f2b(wq[i]);
  else if (i < 65536)   wkb[i - 32768] = f2b(wk[i - 32768]);
  else if (i < 327680)  wvb[i - 65536] = f2b(wv[i - 65536]);
}

// ---------------- transpose [C][N] f32 -> [N][C] bf16 (per batch) ----------------
__global__ __launch_bounds__(256) void k_transpose(const float* __restrict__ src,
                                                   unsigned short* __restrict__ dst) {
  __shared__ float tile[64][65];
  int b = blockIdx.z, c0 = blockIdx.y * 64, n0 = blockIdx.x * 64;
  const float* s = src + (size_t)b * CC * NN;
  unsigned short* d = dst + (size_t)b * NN * CC;
  int t = threadIdx.x;
#pragma unroll
  for (int j = 0; j < 4; j++) {
    int idx = t + j * 256, row = idx >> 4, col4 = (idx & 15) * 4;
    f32x4v v4 = *reinterpret_cast<const f32x4v*>(&s[(size_t)(c0 + row) * NN + n0 + col4]);
    tile[row][col4 + 0] = v4.x; tile[row][col4 + 1] = v4.y;
    tile[row][col4 + 2] = v4.z; tile[row][col4 + 3] = v4.w;
  }
  __syncthreads();
#pragma unroll
  for (int j = 0; j < 4; j++) {
    int idx = t + j * 256, nrow = idx >> 4, c4 = (idx & 15) * 4;
    ushort4 o;
    o.x = f2b(tile[c4 + 0][nrow]); o.y = f2b(tile[c4 + 1][nrow]);
    o.z = f2b(tile[c4 + 2][nrow]); o.w = f2b(tile[c4 + 3][nrow]);
    *reinterpret_cast<ushort4*>(&d[(size_t)(n0 + nrow) * CC + c0 + c4]) = o;
  }
}

// ---------------- Q/K projection: [M=16384][512] x [64][512]^T -> [M][64] bf16 ----------------
__global__ __launch_bounds__(256) void k_proj64(const unsigned short* __restrict__ aT,
                                                const unsigned short* __restrict__ wb,
                                                const float* __restrict__ bias,
                                                unsigned short* __restrict__ out, float scale) {
  int wave = threadIdx.x >> 6, l = threadIdx.x & 63;
  int r0 = blockIdx.x * 64 + wave * 16;
  int lr = l & 15, lk = l >> 4;
  const unsigned short* arow = aT + (size_t)(r0 + lr) * CC + lk * 8;
  f32x4 acc[4] = {};
  for (int ks = 0; ks < 16; ks++) {
    bf16x8 a = ldb8(arow + ks * 32);
#pragma unroll
    for (int cg = 0; cg < 4; cg++) {
      bf16x8 bfr = ldb8(wb + (size_t)(cg * 16 + lr) * CC + ks * 32 + lk * 8);
      acc[cg] = MFMA16(a, bfr, acc[cg]);
    }
  }
#pragma unroll
  for (int cg = 0; cg < 4; cg++) {
    int o = cg * 16 + lr;
    float bv = bias[o];
#pragma unroll
    for (int i = 0; i < 4; i++) {
      int row = r0 + lk * 4 + i;
      out[(size_t)row * C8V + o] = f2b((acc[cg][i] + bv) * scale);
    }
  }
}

// ---------------- V projection: wv[512][512] x xT[b][N][512] -> v[b][512][N] bf16 ----------------
__global__ __launch_bounds__(256) void k_projv(const unsigned short* __restrict__ wvb,
                                               const unsigned short* __restrict__ xT,
                                               const float* __restrict__ bv,
                                               unsigned short* __restrict__ v) {
  int b = blockIdx.z, c0 = blockIdx.y * 64;
  int wave = threadIdx.x >> 6, l = threadIdx.x & 63;
  int n0 = blockIdx.x * 256 + wave * 64;
  int lr = l & 15, lk = l >> 4;
  const unsigned short* xb = xT + (size_t)b * NN * CC;
  f32x4 acc[4][4] = {};
  for (int ks = 0; ks < 16; ks++) {
    bf16x8 a[4], bfr[4];
#pragma unroll
    for (int rg = 0; rg < 4; rg++)
      a[rg] = ldb8(wvb + (size_t)(c0 + rg * 16 + lr) * CC + ks * 32 + lk * 8);
#pragma unroll
    for (int cg = 0; cg < 4; cg++)
      bfr[cg] = ldb8(xb + (size_t)(n0 + cg * 16 + lr) * CC + ks * 32 + lk * 8);
#pragma unroll
    for (int rg = 0; rg < 4; rg++)
#pragma unroll
      for (int cg = 0; cg < 4; cg++)
        acc[rg][cg] = MFMA16(a[rg], bfr[cg], acc[rg][cg]);
  }
  unsigned short* vb = v + (size_t)b * CC * NN;
#pragma unroll
  for (int rg = 0; rg < 4; rg++)
#pragma unroll
    for (int i = 0; i < 4; i++) {
      int row = c0 + rg * 16 + lk * 4 + i;
      float bias = bv[row];
#pragma unroll
      for (int cg = 0; cg < 4; cg++) {
        int col = n0 + cg * 16 + lr;
        vb[(size_t)row * NN + col] = f2b(acc[rg][cg][i] + bias);
      }
    }
}

// ---------------- fused energy + softmax -> attention fp32 ----------------
// q pre-scaled by log2(e); softmax is shift-invariant, energies O(+-15),
// so no max subtraction needed. 512-thr blocks: 2 row-groups (16 rows each)
// x 4 column-quarters -> 4 waves/SIMD for latency hiding. Partial row sums
// combined across the 4 column waves via LDS.
__global__ __launch_bounds__(512) void k_att(const unsigned short* __restrict__ q,
                                             const unsigned short* __restrict__ kt,
                                             float* __restrict__ att) {
  __shared__ float psum[8][16];
  int b = blockIdx.y;
  int w = threadIdx.x >> 6, l = threadIdx.x & 63;
  int rg = w >> 2, cq = w & 3;
  int r0 = blockIdx.x * 32 + rg * 16;
  int lr = l & 15, lk = l >> 4;
  const unsigned short* qp = q + (size_t)(b * NN + r0 + lr) * C8V + lk * 8;
  bf16x8 aq0 = ldb8(qp);
  bf16x8 aq1 = ldb8(qp + 32);
  const unsigned short* ktb = kt + (size_t)b * NN * C8V;
  int jt0 = cq * 16;

  float lsum[4] = {0.f, 0.f, 0.f, 0.f};
  for (int jt = jt0; jt < jt0 + 16; jt++) {               // pass 1: partial row sums
    f32x4 acc[4] = {};
#pragma unroll
    for (int cg = 0; cg < 4; cg++) {
      const unsigned short* kp = ktb + (size_t)(jt * 64 + cg * 16 + lr) * C8V + lk * 8;
      acc[cg] = MFMA16(aq0, ldb8(kp), acc[cg]);
      acc[cg] = MFMA16(aq1, ldb8(kp + 32), acc[cg]);
    }
#pragma unroll
    for (int i = 0; i < 4; i++)
      lsum[i] += (EXP2(acc[0][i]) + EXP2(acc[1][i])) + (EXP2(acc[2][i]) + EXP2(acc[3][i]));
  }
#pragma unroll
  for (int i = 0; i < 4; i++) {
#pragma unroll
    for (int mm = 1; mm < 16; mm <<= 1) lsum[i] += __shfl_xor(lsum[i], mm);
  }
  if (lr == 0) {
#pragma unroll
    for (int i = 0; i < 4; i++) psum[w][lk * 4 + i] = lsum[i];
  }
  __syncthreads();
  float inv[4];
#pragma unroll
  for (int i = 0; i < 4; i++) {
    int rr = lk * 4 + i;
    inv[i] = 1.0f / (psum[rg * 4 + 0][rr] + psum[rg * 4 + 1][rr] +
                     psum[rg * 4 + 2][rr] + psum[rg * 4 + 3][rr]);
  }

  float* ab = att + (size_t)b * NN * NN;
  for (int jt = jt0; jt < jt0 + 16; jt++) {               // pass 2: write normalized
    f32x4 acc[4] = {};
#pragma unroll
    for (int cg = 0; cg < 4; cg++) {
      const unsigned short* kp = ktb + (size_t)(jt * 64 + cg * 16 + lr) * C8V + lk * 8;
      acc[cg] = MFMA16(aq0, ldb8(kp), acc[cg]);
      acc[cg] = MFMA16(aq1, ldb8(kp + 32), acc[cg]);
    }
#pragma unroll
    for (int cg = 0; cg < 4; cg++) {
      int col = jt * 64 + cg * 16 + lr;
#pragma unroll
      for (int i = 0; i < 4; i++) {
        int row = r0 + lk * 4 + i;
        __builtin_nontemporal_store(EXP2(acc[cg][i]) * inv[i], &ab[(size_t)row * NN + col]);
      }
    }
  }
}

// ---------------- PV + epilogue: out = gamma * (v @ att^T) + x ----------------
// 256 blocks, 1/CU, XCD-pinned (batch b owns XCDs {2b,2b+1}; v[b]=4MB stays
// L2-resident). No LDS, no barriers: each lane loads its att B-fragment
// directly (2x f32x4 nontemporal) and converts in-register -> waves run
// independently and the compiler pipelines the kc loop across iterations.
__global__ __launch_bounds__(512) void k_pv(const unsigned short* __restrict__ v,
                                            const float* __restrict__ att,
                                            const float* __restrict__ x,
                                            const float* __restrict__ gamma,
                                            float* __restrict__ out) {
  int bid = blockIdx.x;
  int b = (bid & 7) >> 1;                       // XCD id = bid % 8 (round-robin)
  int m0 = ((bid >> 3) * 2 + (bid & 1)) * 64;   // 64 m-tiles per batch
  int t = threadIdx.x, wave = t >> 6, l = t & 63, lr = l & 15, lk = l >> 4;
  int c0 = wave * 64;
  const unsigned short* vb = v + (size_t)b * CC * NN;
  const float* ab = att + ((size_t)b * NN + m0) * NN;

  f32x4 acc[4][4] = {};
  for (int kc = 0; kc < 64; kc++) {
#pragma unroll
    for (int ks = 0; ks < 2; ks++) {
      int kk = kc * 64 + ks * 32 + lk * 8;
      bf16x8 bfr[4], a[4];
#pragma unroll
      for (int cg = 0; cg < 4; cg++) {
        const float* ap = ab + (size_t)(cg * 16 + lr) * NN + kk;
        bfr[cg] = cvt8(ntl4(ap), ntl4(ap + 4));
      }
#pragma unroll
      for (int rg = 0; rg < 4; rg++)
        a[rg] = ldb8(vb + (size_t)(c0 + rg * 16 + lr) * NN + kk);
#pragma unroll
      for (int rg = 0; rg < 4; rg++)
#pragma unroll
        for (int cg = 0; cg < 4; cg++)
          acc[rg][cg] = MFMA16(a[rg], bfr[cg], acc[rg][cg]);
    }
  }

  float g = gamma[0];
  const float* xb = x + (size_t)b * CC * NN;
  float* ob = out + (size_t)b * CC * NN;
#pragma unroll
  for (int rg = 0; rg < 4; rg++)
#pragma unroll
    for (int i = 0; i < 4; i++) {
      int row = c0 + rg * 16 + lk * 4 + i;
#pragma unroll
      for (int cg = 0; cg < 4; cg++) {
        int col = m0 + cg * 16 + lr;
        size_t off = (size_t)row * NN + col;
        float xv = __builtin_nontemporal_load(&xb[off]);
        __builtin_nontemporal_store(g * acc[rg][cg][i] + xv, &ob[off]);
      }
    }
}

extern "C" void kernel_launch(void* const* d_in, const int* in_sizes, int n_in,
                              void* d_out, int out_size, void* d_ws, size_t ws_size,
                              hipStream_t stream) {
  const float* x  = (const float*)d_in[0];
  const float* y  = (const float*)d_in[1];
  const float* wq = (const float*)d_in[2];
  const float* bq = (const float*)d_in[3];
  const float* wk = (const float*)d_in[4];
  const float* bk = (const float*)d_in[5];
  const float* wv = (const float*)d_in[6];
  const float* bv = (const float*)d_in[7];
  const float* gamma = (const float*)d_in[8];

  float* out = (float*)d_out;
  float* att = out + (size_t)BB * CC * NN;   // attention region of d_out

  // workspace layout (bytes)
  char* ws = (char*)d_ws;
  unsigned short* yT  = (unsigned short*)(ws);                 // 16 MiB  [B][N][C] bf16
  unsigned short* xT  = (unsigned short*)(ws + 16777216);      // 16 MiB
  unsigned short* q   = (unsigned short*)(ws + 33554432);      // 2 MiB   [B*N][64]
  unsigned short* kt  = (unsigned short*)(ws + 35651584);      // 2 MiB   [B*N][64]
  unsigned short* v   = (unsigned short*)(ws + 37748736);      // 16 MiB  [B][C][N]
  unsigned short* wqb = (unsigned short*)(ws + 54525952);      // 64 KiB
  unsigned short* wkb = (unsigned short*)(ws + 54591488);      // 64 KiB
  unsigned short* wvb = (unsigned short*)(ws + 54657024);      // 512 KiB
  if (ws_size < 55181312u) return;  // insufficient scratch -> fail loudly

  k_cvt_w<<<1280, 256, 0, stream>>>(wq, wk, wv, wqb, wkb, wvb);
  k_transpose<<<dim3(64, 8, 4), 256, 0, stream>>>(y, yT);
  k_transpose<<<dim3(64, 8, 4), 256, 0, stream>>>(x, xT);
  k_proj64<<<256, 256, 0, stream>>>(yT, wqb, bq, q, 1.44269504088896f);  // q pre-scaled by log2(e)
  k_proj64<<<256, 256, 0, stream>>>(yT, wkb, bk, kt, 1.0f);
  k_projv<<<dim3(16, 8, 4), 256, 0, stream>>>(wvb, xT, bv, v);
  k_att<<<dim3(128, 4), 512, 0, stream>>>(q, kt, att);
  k_pv<<<256, 512, 0, stream>>>(v, att, x, gamma, out);
}

// Round 5
// 483.562 us; speedup vs baseline: 1.4895x; 1.4895x over previous
//
#include <hip/hip_runtime.h>

// SelfAttn (SAGAN block): B=4, C=512, N=4096, C8=64
// out = gamma * (V @ softmax(Q K^T)^T) + x ; also outputs attention [B,N,N].
// All GEMMs via v_mfma_f32_16x16x32_bf16; fp32 accumulate.

#define BB 4
#define CC 512
#define NN 4096
#define C8V 64

typedef __bf16 bf16x8 __attribute__((ext_vector_type(8)));
typedef float f32x4 __attribute__((ext_vector_type(4)));
typedef float f32x4v __attribute__((ext_vector_type(4)));   // for nontemporal builtins
typedef unsigned short u16x8 __attribute__((ext_vector_type(8)));

#if __has_builtin(__builtin_amdgcn_exp2f)
#define EXP2(x) __builtin_amdgcn_exp2f(x)
#else
#define EXP2(x) exp2f(x)
#endif

#define MFMA16(a, b, c) __builtin_amdgcn_mfma_f32_16x16x32_bf16((a), (b), (c), 0, 0, 0)

__device__ __forceinline__ unsigned short f2b(float f) {
  union { float f; unsigned u; } x; x.f = f;
  unsigned u = x.u;
  u += 0x7fffu + ((u >> 16) & 1u);   // RNE round to bf16
  return (unsigned short)(u >> 16);
}

__device__ __forceinline__ bf16x8 ldb8(const unsigned short* p) {
  return *reinterpret_cast<const bf16x8*>(p);
}

__device__ __forceinline__ f32x4v ntl4(const float* p) {
  return __builtin_nontemporal_load(reinterpret_cast<const f32x4v*>(p));
}

// ---------------- weights fp32 -> bf16 ----------------
__global__ __launch_bounds__(256) void k_cvt_w(
    const float* __restrict__ wq, const float* __restrict__ wk, const float* __restrict__ wv,
    unsigned short* __restrict__ wqb, unsigned short* __restrict__ wkb, unsigned short* __restrict__ wvb) {
  int i = blockIdx.x * 256 + threadIdx.x;
  if (i < 32768)        wqb[i] = f2b(wq[i]);
  else if (i < 65536)   wkb[i - 32768] = f2b(wk[i - 32768]);
  else if (i < 327680)  wvb[i - 65536] = f2b(wv[i - 65536]);
}

// ---------------- transpose [C][N] f32 -> [N][C] bf16 (per batch) ----------------
__global__ __launch_bounds__(256) void k_transpose(const float* __restrict__ src,
                                                   unsigned short* __restrict__ dst) {
  __shared__ float tile[64][65];
  int b = blockIdx.z, c0 = blockIdx.y * 64, n0 = blockIdx.x * 64;
  const float* s = src + (size_t)b * CC * NN;
  unsigned short* d = dst + (size_t)b * NN * CC;
  int t = threadIdx.x;
#pragma unroll
  for (int j = 0; j < 4; j++) {
    int idx = t + j * 256, row = idx >> 4, col4 = (idx & 15) * 4;
    f32x4v v4 = *reinterpret_cast<const f32x4v*>(&s[(size_t)(c0 + row) * NN + n0 + col4]);
    tile[row][col4 + 0] = v4.x; tile[row][col4 + 1] = v4.y;
    tile[row][col4 + 2] = v4.z; tile[row][col4 + 3] = v4.w;
  }
  __syncthreads();
#pragma unroll
  for (int j = 0; j < 4; j++) {
    int idx = t + j * 256, nrow = idx >> 4, c4 = (idx & 15) * 4;
    ushort4 o;
    o.x = f2b(tile[c4 + 0][nrow]); o.y = f2b(tile[c4 + 1][nrow]);
    o.z = f2b(tile[c4 + 2][nrow]); o.w = f2b(tile[c4 + 3][nrow]);
    *reinterpret_cast<ushort4*>(&d[(size_t)(n0 + nrow) * CC + c0 + c4]) = o;
  }
}

// ---------------- Q/K projection: [M=16384][512] x [64][512]^T -> [M][64] bf16 ----------------
__global__ __launch_bounds__(256) void k_proj64(const unsigned short* __restrict__ aT,
                                                const unsigned short* __restrict__ wb,
                                                const float* __restrict__ bias,
                                                unsigned short* __restrict__ out, float scale) {
  int wave = threadIdx.x >> 6, l = threadIdx.x & 63;
  int r0 = blockIdx.x * 64 + wave * 16;
  int lr = l & 15, lk = l >> 4;
  const unsigned short* arow = aT + (size_t)(r0 + lr) * CC + lk * 8;
  f32x4 acc[4] = {};
  for (int ks = 0; ks < 16; ks++) {
    bf16x8 a = ldb8(arow + ks * 32);
#pragma unroll
    for (int cg = 0; cg < 4; cg++) {
      bf16x8 bfr = ldb8(wb + (size_t)(cg * 16 + lr) * CC + ks * 32 + lk * 8);
      acc[cg] = MFMA16(a, bfr, acc[cg]);
    }
  }
#pragma unroll
  for (int cg = 0; cg < 4; cg++) {
    int o = cg * 16 + lr;
    float bv = bias[o];
#pragma unroll
    for (int i = 0; i < 4; i++) {
      int row = r0 + lk * 4 + i;
      out[(size_t)row * C8V + o] = f2b((acc[cg][i] + bv) * scale);
    }
  }
}

// ---------------- V projection: wv[512][512] x xT[b][N][512] -> v[b][512][N] bf16 ----------------
__global__ __launch_bounds__(256) void k_projv(const unsigned short* __restrict__ wvb,
                                               const unsigned short* __restrict__ xT,
                                               const float* __restrict__ bv,
                                               unsigned short* __restrict__ v) {
  int b = blockIdx.z, c0 = blockIdx.y * 64;
  int wave = threadIdx.x >> 6, l = threadIdx.x & 63;
  int n0 = blockIdx.x * 256 + wave * 64;
  int lr = l & 15, lk = l >> 4;
  const unsigned short* xb = xT + (size_t)b * NN * CC;
  f32x4 acc[4][4] = {};
  for (int ks = 0; ks < 16; ks++) {
    bf16x8 a[4], bfr[4];
#pragma unroll
    for (int rg = 0; rg < 4; rg++)
      a[rg] = ldb8(wvb + (size_t)(c0 + rg * 16 + lr) * CC + ks * 32 + lk * 8);
#pragma unroll
    for (int cg = 0; cg < 4; cg++)
      bfr[cg] = ldb8(xb + (size_t)(n0 + cg * 16 + lr) * CC + ks * 32 + lk * 8);
#pragma unroll
    for (int rg = 0; rg < 4; rg++)
#pragma unroll
      for (int cg = 0; cg < 4; cg++)
        acc[rg][cg] = MFMA16(a[rg], bfr[cg], acc[rg][cg]);
  }
  unsigned short* vb = v + (size_t)b * CC * NN;
#pragma unroll
  for (int rg = 0; rg < 4; rg++)
#pragma unroll
    for (int i = 0; i < 4; i++) {
      int row = c0 + rg * 16 + lk * 4 + i;
      float bias = bv[row];
#pragma unroll
      for (int cg = 0; cg < 4; cg++) {
        int col = n0 + cg * 16 + lr;
        vb[(size_t)row * NN + col] = f2b(acc[rg][cg][i] + bias);
      }
    }
}

// ---------------- fused energy + softmax -> attention fp32 ----------------
// q pre-scaled by log2(e); softmax is shift-invariant, energies O(+-15),
// so no max subtraction needed. 512-thr blocks: 2 row-groups (16 rows each)
// x 4 column-quarters -> 4 waves/SIMD for latency hiding. Partial row sums
// combined across the 4 column waves via LDS.
__global__ __launch_bounds__(512) void k_att(const unsigned short* __restrict__ q,
                                             const unsigned short* __restrict__ kt,
                                             float* __restrict__ att) {
  __shared__ float psum[8][16];
  int b = blockIdx.y;
  int w = threadIdx.x >> 6, l = threadIdx.x & 63;
  int rg = w >> 2, cq = w & 3;
  int r0 = blockIdx.x * 32 + rg * 16;
  int lr = l & 15, lk = l >> 4;
  const unsigned short* qp = q + (size_t)(b * NN + r0 + lr) * C8V + lk * 8;
  bf16x8 aq0 = ldb8(qp);
  bf16x8 aq1 = ldb8(qp + 32);
  const unsigned short* ktb = kt + (size_t)b * NN * C8V;
  int jt0 = cq * 16;

  float lsum[4] = {0.f, 0.f, 0.f, 0.f};
  for (int jt = jt0; jt < jt0 + 16; jt++) {               // pass 1: partial row sums
    f32x4 acc[4] = {};
#pragma unroll
    for (int cg = 0; cg < 4; cg++) {
      const unsigned short* kp = ktb + (size_t)(jt * 64 + cg * 16 + lr) * C8V + lk * 8;
      acc[cg] = MFMA16(aq0, ldb8(kp), acc[cg]);
      acc[cg] = MFMA16(aq1, ldb8(kp + 32), acc[cg]);
    }
#pragma unroll
    for (int i = 0; i < 4; i++)
      lsum[i] += (EXP2(acc[0][i]) + EXP2(acc[1][i])) + (EXP2(acc[2][i]) + EXP2(acc[3][i]));
  }
#pragma unroll
  for (int i = 0; i < 4; i++) {
#pragma unroll
    for (int mm = 1; mm < 16; mm <<= 1) lsum[i] += __shfl_xor(lsum[i], mm);
  }
  if (lr == 0) {
#pragma unroll
    for (int i = 0; i < 4; i++) psum[w][lk * 4 + i] = lsum[i];
  }
  __syncthreads();
  float inv[4];
#pragma unroll
  for (int i = 0; i < 4; i++) {
    int rr = lk * 4 + i;
    inv[i] = 1.0f / (psum[rg * 4 + 0][rr] + psum[rg * 4 + 1][rr] +
                     psum[rg * 4 + 2][rr] + psum[rg * 4 + 3][rr]);
  }

  float* ab = att + (size_t)b * NN * NN;
  for (int jt = jt0; jt < jt0 + 16; jt++) {               // pass 2: write normalized
    f32x4 acc[4] = {};
#pragma unroll
    for (int cg = 0; cg < 4; cg++) {
      const unsigned short* kp = ktb + (size_t)(jt * 64 + cg * 16 + lr) * C8V + lk * 8;
      acc[cg] = MFMA16(aq0, ldb8(kp), acc[cg]);
      acc[cg] = MFMA16(aq1, ldb8(kp + 32), acc[cg]);
    }
#pragma unroll
    for (int cg = 0; cg < 4; cg++) {
      int col = jt * 64 + cg * 16 + lr;
#pragma unroll
      for (int i = 0; i < 4; i++) {
        int row = r0 + lk * 4 + i;
        __builtin_nontemporal_store(EXP2(acc[cg][i]) * inv[i], &ab[(size_t)row * NN + col]);
      }
    }
  }
}

// ---------------- PV + epilogue: out = gamma * (v @ att^T) + x ----------------
// Tile 32m x 512c, grid 512 = 2 blocks/CU (so one block computes while the
// other drains its staging loads at the barrier). XCD-pinned: batch b owns
// XCDs {2b,2b+1}; v[b]=4MB stays L2-resident; att/x/out are nontemporal.
// att staged via explicit 1-deep register prefetch -> LDS double buffer
// (XOR-swizzled), ONE barrier per kc. v read direct from L2.
__global__ __launch_bounds__(512, 4) void k_pv(const unsigned short* __restrict__ v,
                                               const float* __restrict__ att,
                                               const float* __restrict__ x,
                                               const float* __restrict__ gamma,
                                               float* __restrict__ out) {
  __shared__ unsigned short smB[2][32 * 64];
  int bid = blockIdx.x;
  int b = (bid & 7) >> 1;                        // XCD id = bid % 8 (round-robin)
  int m0 = ((bid >> 3) * 2 + (bid & 1)) * 32;    // 128 m-tiles of 32 rows per batch
  int t = threadIdx.x, wave = t >> 6, l = t & 63, lr = l & 15, lk = l >> 4;
  int c0 = wave * 64;
  int mrow = t >> 4, col4 = t & 15;              // staging: 32 rows x 16 f32x4
  const float* attb = att + ((size_t)b * NN + m0 + mrow) * NN + col4 * 4;
  const unsigned short* vb = v + (size_t)b * CC * NN;
  int wbyte = mrow * 128 + ((col4 * 8) ^ ((mrow & 7) << 4));  // swizzled write addr

  // prologue: stage kc=0
  f32x4v g = ntl4(attb);
  {
    ushort4 pk;
    pk.x = f2b(g.x); pk.y = f2b(g.y); pk.z = f2b(g.z); pk.w = f2b(g.w);
    *reinterpret_cast<ushort4*>(reinterpret_cast<char*>(&smB[0][0]) + wbyte) = pk;
  }
  __syncthreads();

  f32x4 acc[4][2] = {};
  for (int kc = 0; kc < 64; kc++) {
    int cur = kc & 1;
    if (kc < 63) g = ntl4(attb + (kc + 1) * 64);   // prefetch next chunk (regs)
#pragma unroll
    for (int ks = 0; ks < 2; ks++) {
      bf16x8 a[4], bfr[2];
#pragma unroll
      for (int cg = 0; cg < 2; cg++) {
        int mr = cg * 16 + lr;
        int rb = (ks * 64 + lk * 16) ^ ((mr & 7) << 4);
        bfr[cg] = *reinterpret_cast<const bf16x8*>(
            reinterpret_cast<const char*>(&smB[cur][0]) + mr * 128 + rb);
      }
#pragma unroll
      for (int rg = 0; rg < 4; rg++)
        a[rg] = ldb8(vb + (size_t)(c0 + rg * 16 + lr) * NN + kc * 64 + ks * 32 + lk * 8);
#pragma unroll
      for (int rg = 0; rg < 4; rg++)
#pragma unroll
        for (int cg = 0; cg < 2; cg++)
          acc[rg][cg] = MFMA16(a[rg], bfr[cg], acc[rg][cg]);
    }
    if (kc < 63) {                                  // write prefetched chunk
      ushort4 pk;
      pk.x = f2b(g.x); pk.y = f2b(g.y); pk.z = f2b(g.z); pk.w = f2b(g.w);
      *reinterpret_cast<ushort4*>(reinterpret_cast<char*>(&smB[cur ^ 1][0]) + wbyte) = pk;
    }
    __syncthreads();
  }

  float gm = gamma[0];
  const float* xb = x + (size_t)b * CC * NN;
  float* ob = out + (size_t)b * CC * NN;
#pragma unroll
  for (int rg = 0; rg < 4; rg++)
#pragma unroll
    for (int i = 0; i < 4; i++) {
      int row = c0 + rg * 16 + lk * 4 + i;
#pragma unroll
      for (int cg = 0; cg < 2; cg++) {
        int col = m0 + cg * 16 + lr;
        size_t off = (size_t)row * NN + col;
        float xv = __builtin_nontemporal_load(&xb[off]);
        __builtin_nontemporal_store(gm * acc[rg][cg][i] + xv, &ob[off]);
      }
    }
}

extern "C" void kernel_launch(void* const* d_in, const int* in_sizes, int n_in,
                              void* d_out, int out_size, void* d_ws, size_t ws_size,
                              hipStream_t stream) {
  const float* x  = (const float*)d_in[0];
  const float* y  = (const float*)d_in[1];
  const float* wq = (const float*)d_in[2];
  const float* bq = (const float*)d_in[3];
  const float* wk = (const float*)d_in[4];
  const float* bk = (const float*)d_in[5];
  const float* wv = (const float*)d_in[6];
  const float* bv = (const float*)d_in[7];
  const float* gamma = (const float*)d_in[8];

  float* out = (float*)d_out;
  float* att = out + (size_t)BB * CC * NN;   // attention region of d_out

  // workspace layout (bytes)
  char* ws = (char*)d_ws;
  unsigned short* yT  = (unsigned short*)(ws);                 // 16 MiB  [B][N][C] bf16
  unsigned short* xT  = (unsigned short*)(ws + 16777216);      // 16 MiB
  unsigned short* q   = (unsigned short*)(ws + 33554432);      // 2 MiB   [B*N][64]
  unsigned short* kt  = (unsigned short*)(ws + 35651584);      // 2 MiB   [B*N][64]
  unsigned short* v   = (unsigned short*)(ws + 37748736);      // 16 MiB  [B][C][N]
  unsigned short* wqb = (unsigned short*)(ws + 54525952);      // 64 KiB
  unsigned short* wkb = (unsigned short*)(ws + 54591488);      // 64 KiB
  unsigned short* wvb = (unsigned short*)(ws + 54657024);      // 512 KiB
  if (ws_size < 55181312u) return;  // insufficient scratch -> fail loudly

  k_cvt_w<<<1280, 256, 0, stream>>>(wq, wk, wv, wqb, wkb, wvb);
  k_transpose<<<dim3(64, 8, 4), 256, 0, stream>>>(y, yT);
  k_transpose<<<dim3(64, 8, 4), 256, 0, stream>>>(x, xT);
  k_proj64<<<256, 256, 0, stream>>>(yT, wqb, bq, q, 1.44269504088896f);  // q pre-scaled by log2(e)
  k_proj64<<<256, 256, 0, stream>>>(yT, wkb, bk, kt, 1.0f);
  k_projv<<<dim3(16, 8, 4), 256, 0, stream>>>(wvb, xT, bv, v);
  k_att<<<dim3(128, 4), 512, 0, stream>>>(q, kt, att);
  k_pv<<<512, 512, 0, stream>>>(v, att, x, gamma, out);
}

// Round 6
// 379.193 us; speedup vs baseline: 1.8995x; 1.2752x over previous
//
#include <hip/hip_runtime.h>

// SelfAttn (SAGAN block): B=4, C=512, N=4096, C8=64
// out = gamma * (V @ softmax(Q K^T)^T) + x ; also outputs attention [B,N,N].
// All GEMMs via v_mfma_f32_16x16x32_bf16; fp32 accumulate.

#define BB 4
#define CC 512
#define NN 4096
#define C8V 64

typedef __bf16 bf16x8 __attribute__((ext_vector_type(8)));
typedef float f32x4 __attribute__((ext_vector_type(4)));
typedef float f32x4v __attribute__((ext_vector_type(4)));   // for nontemporal builtins
typedef unsigned short u16x8 __attribute__((ext_vector_type(8)));

#if __has_builtin(__builtin_amdgcn_exp2f)
#define EXP2(x) __builtin_amdgcn_exp2f(x)
#else
#define EXP2(x) exp2f(x)
#endif

#define MFMA16(a, b, c) __builtin_amdgcn_mfma_f32_16x16x32_bf16((a), (b), (c), 0, 0, 0)

__device__ __forceinline__ unsigned short f2b(float f) {
  union { float f; unsigned u; } x; x.f = f;
  unsigned u = x.u;
  u += 0x7fffu + ((u >> 16) & 1u);   // RNE round to bf16
  return (unsigned short)(u >> 16);
}

__device__ __forceinline__ bf16x8 ldb8(const unsigned short* p) {
  return *reinterpret_cast<const bf16x8*>(p);
}

__device__ __forceinline__ f32x4v ntl4(const float* p) {
  return __builtin_nontemporal_load(reinterpret_cast<const f32x4v*>(p));
}

// ---------------- weights fp32 -> bf16 ----------------
__global__ __launch_bounds__(256) void k_cvt_w(
    const float* __restrict__ wq, const float* __restrict__ wk, const float* __restrict__ wv,
    unsigned short* __restrict__ wqb, unsigned short* __restrict__ wkb, unsigned short* __restrict__ wvb) {
  int i = blockIdx.x * 256 + threadIdx.x;
  if (i < 32768)        wqb[i] = f2b(wq[i]);
  else if (i < 65536)   wkb[i - 32768] = f2b(wk[i - 32768]);
  else if (i < 327680)  wvb[i - 65536] = f2b(wv[i - 65536]);
}

// ---------------- transpose [C][N] f32 -> [N][C] bf16 (per batch) ----------------
__global__ __launch_bounds__(256) void k_transpose(const float* __restrict__ src,
                                                   unsigned short* __restrict__ dst) {
  __shared__ float tile[64][65];
  int b = blockIdx.z, c0 = blockIdx.y * 64, n0 = blockIdx.x * 64;
  const float* s = src + (size_t)b * CC * NN;
  unsigned short* d = dst + (size_t)b * NN * CC;
  int t = threadIdx.x;
#pragma unroll
  for (int j = 0; j < 4; j++) {
    int idx = t + j * 256, row = idx >> 4, col4 = (idx & 15) * 4;
    f32x4v v4 = *reinterpret_cast<const f32x4v*>(&s[(size_t)(c0 + row) * NN + n0 + col4]);
    tile[row][col4 + 0] = v4.x; tile[row][col4 + 1] = v4.y;
    tile[row][col4 + 2] = v4.z; tile[row][col4 + 3] = v4.w;
  }
  __syncthreads();
#pragma unroll
  for (int j = 0; j < 4; j++) {
    int idx = t + j * 256, nrow = idx >> 4, c4 = (idx & 15) * 4;
    ushort4 o;
    o.x = f2b(tile[c4 + 0][nrow]); o.y = f2b(tile[c4 + 1][nrow]);
    o.z = f2b(tile[c4 + 2][nrow]); o.w = f2b(tile[c4 + 3][nrow]);
    *reinterpret_cast<ushort4*>(&d[(size_t)(n0 + nrow) * CC + c0 + c4]) = o;
  }
}

// ---------------- Q/K projection: [M=16384][512] x [64][512]^T -> [M][64] bf16 ----------------
__global__ __launch_bounds__(256) void k_proj64(const unsigned short* __restrict__ aT,
                                                const unsigned short* __restrict__ wb,
                                                const float* __restrict__ bias,
                                                unsigned short* __restrict__ out, float scale) {
  int wave = threadIdx.x >> 6, l = threadIdx.x & 63;
  int r0 = blockIdx.x * 64 + wave * 16;
  int lr = l & 15, lk = l >> 4;
  const unsigned short* arow = aT + (size_t)(r0 + lr) * CC + lk * 8;
  f32x4 acc[4] = {};
  for (int ks = 0; ks < 16; ks++) {
    bf16x8 a = ldb8(arow + ks * 32);
#pragma unroll
    for (int cg = 0; cg < 4; cg++) {
      bf16x8 bfr = ldb8(wb + (size_t)(cg * 16 + lr) * CC + ks * 32 + lk * 8);
      acc[cg] = MFMA16(a, bfr, acc[cg]);
    }
  }
#pragma unroll
  for (int cg = 0; cg < 4; cg++) {
    int o = cg * 16 + lr;
    float bv = bias[o];
#pragma unroll
    for (int i = 0; i < 4; i++) {
      int row = r0 + lk * 4 + i;
      out[(size_t)row * C8V + o] = f2b((acc[cg][i] + bv) * scale);
    }
  }
}

// ---------------- V projection: wv[512][512] x xT[b][N][512] -> v[b][512][N] bf16 ----------------
__global__ __launch_bounds__(256) void k_projv(const unsigned short* __restrict__ wvb,
                                               const unsigned short* __restrict__ xT,
                                               const float* __restrict__ bv,
                                               unsigned short* __restrict__ v) {
  int b = blockIdx.z, c0 = blockIdx.y * 64;
  int wave = threadIdx.x >> 6, l = threadIdx.x & 63;
  int n0 = blockIdx.x * 256 + wave * 64;
  int lr = l & 15, lk = l >> 4;
  const unsigned short* xb = xT + (size_t)b * NN * CC;
  f32x4 acc[4][4] = {};
  for (int ks = 0; ks < 16; ks++) {
    bf16x8 a[4], bfr[4];
#pragma unroll
    for (int rg = 0; rg < 4; rg++)
      a[rg] = ldb8(wvb + (size_t)(c0 + rg * 16 + lr) * CC + ks * 32 + lk * 8);
#pragma unroll
    for (int cg = 0; cg < 4; cg++)
      bfr[cg] = ldb8(xb + (size_t)(n0 + cg * 16 + lr) * CC + ks * 32 + lk * 8);
#pragma unroll
    for (int rg = 0; rg < 4; rg++)
#pragma unroll
      for (int cg = 0; cg < 4; cg++)
        acc[rg][cg] = MFMA16(a[rg], bfr[cg], acc[rg][cg]);
  }
  unsigned short* vb = v + (size_t)b * CC * NN;
#pragma unroll
  for (int rg = 0; rg < 4; rg++)
#pragma unroll
    for (int i = 0; i < 4; i++) {
      int row = c0 + rg * 16 + lk * 4 + i;
      float bias = bv[row];
#pragma unroll
      for (int cg = 0; cg < 4; cg++) {
        int col = n0 + cg * 16 + lr;
        vb[(size_t)row * NN + col] = f2b(acc[rg][cg][i] + bias);
      }
    }
}

// ---------------- fused energy + softmax -> attention fp32 ----------------
// q pre-scaled by log2(e); softmax is shift-invariant, energies O(+-15),
// so no max subtraction needed. 512-thr blocks: 2 row-groups (16 rows each)
// x 4 column-quarters -> 4 waves/SIMD for latency hiding. Partial row sums
// combined across the 4 column waves via LDS.
__global__ __launch_bounds__(512) void k_att(const unsigned short* __restrict__ q,
                                             const unsigned short* __restrict__ kt,
                                             float* __restrict__ att) {
  __shared__ float psum[8][16];
  int b = blockIdx.y;
  int w = threadIdx.x >> 6, l = threadIdx.x & 63;
  int rg = w >> 2, cq = w & 3;
  int r0 = blockIdx.x * 32 + rg * 16;
  int lr = l & 15, lk = l >> 4;
  const unsigned short* qp = q + (size_t)(b * NN + r0 + lr) * C8V + lk * 8;
  bf16x8 aq0 = ldb8(qp);
  bf16x8 aq1 = ldb8(qp + 32);
  const unsigned short* ktb = kt + (size_t)b * NN * C8V;
  int jt0 = cq * 16;

  float lsum[4] = {0.f, 0.f, 0.f, 0.f};
  for (int jt = jt0; jt < jt0 + 16; jt++) {               // pass 1: partial row sums
    f32x4 acc[4] = {};
#pragma unroll
    for (int cg = 0; cg < 4; cg++) {
      const unsigned short* kp = ktb + (size_t)(jt * 64 + cg * 16 + lr) * C8V + lk * 8;
      acc[cg] = MFMA16(aq0, ldb8(kp), acc[cg]);
      acc[cg] = MFMA16(aq1, ldb8(kp + 32), acc[cg]);
    }
#pragma unroll
    for (int i = 0; i < 4; i++)
      lsum[i] += (EXP2(acc[0][i]) + EXP2(acc[1][i])) + (EXP2(acc[2][i]) + EXP2(acc[3][i]));
  }
#pragma unroll
  for (int i = 0; i < 4; i++) {
#pragma unroll
    for (int mm = 1; mm < 16; mm <<= 1) lsum[i] += __shfl_xor(lsum[i], mm);
  }
  if (lr == 0) {
#pragma unroll
    for (int i = 0; i < 4; i++) psum[w][lk * 4 + i] = lsum[i];
  }
  __syncthreads();
  float inv[4];
#pragma unroll
  for (int i = 0; i < 4; i++) {
    int rr = lk * 4 + i;
    inv[i] = 1.0f / (psum[rg * 4 + 0][rr] + psum[rg * 4 + 1][rr] +
                     psum[rg * 4 + 2][rr] + psum[rg * 4 + 3][rr]);
  }

  float* ab = att + (size_t)b * NN * NN;
  for (int jt = jt0; jt < jt0 + 16; jt++) {               // pass 2: write normalized
    f32x4 acc[4] = {};
#pragma unroll
    for (int cg = 0; cg < 4; cg++) {
      const unsigned short* kp = ktb + (size_t)(jt * 64 + cg * 16 + lr) * C8V + lk * 8;
      acc[cg] = MFMA16(aq0, ldb8(kp), acc[cg]);
      acc[cg] = MFMA16(aq1, ldb8(kp + 32), acc[cg]);
    }
#pragma unroll
    for (int cg = 0; cg < 4; cg++) {
      int col = jt * 64 + cg * 16 + lr;
#pragma unroll
      for (int i = 0; i < 4; i++) {
        int row = r0 + lk * 4 + i;
        __builtin_nontemporal_store(EXP2(acc[cg][i]) * inv[i], &ab[(size_t)row * NN + col]);
      }
    }
  }
}

// ---------------- PV + epilogue: out = gamma * (v @ att^T) + x ----------------
// Tile 64m x 512c, grid 256 (1 block/CU), XCD-pinned (batch b owns XCDs
// {2b,2b+1}; v[b]=4MB L2-resident). att staged via DEPTH-4 register prefetch
// queue -> LDS double buffer (XOR-swizzled). Sync is raw s_barrier +
// lgkmcnt(0) ONLY: no vmcnt drain, so the 4 in-flight att loads survive the
// barrier (T3/T4) and HBM latency hides under ~4 iterations of MFMA.
__global__ __launch_bounds__(512, 2) void k_pv(const unsigned short* __restrict__ v,
                                               const float* __restrict__ att,
                                               const float* __restrict__ x,
                                               const float* __restrict__ gamma,
                                               float* __restrict__ out) {
  __shared__ unsigned short smB[2][64 * 64];   // 2 x 8 KiB
  int bid = blockIdx.x;
  int b = (bid & 7) >> 1;                       // XCD id = bid % 8 (round-robin)
  int m0 = ((bid >> 3) * 2 + (bid & 1)) * 64;   // 64 m-tiles per batch
  int t = threadIdx.x, wave = t >> 6, l = t & 63, lr = l & 15, lk = l >> 4;
  int c0 = wave * 64;
  int mrow = t >> 3, col8 = t & 7;              // staging: 64 rows x 8 f32x8
  const float* attb = att + ((size_t)b * NN + m0 + mrow) * NN + col8 * 8;
  const unsigned short* vb = v + (size_t)b * CC * NN;
  int wbyte = mrow * 128 + ((col8 * 16) ^ ((mrow & 7) << 4));  // swizzled write (bytes)

#define STAGE_WR(buf, ga, gb)                                                  \
  {                                                                            \
    u16x8 pk;                                                                  \
    pk[0] = f2b((ga).x); pk[1] = f2b((ga).y); pk[2] = f2b((ga).z);             \
    pk[3] = f2b((ga).w); pk[4] = f2b((gb).x); pk[5] = f2b((gb).y);             \
    pk[6] = f2b((gb).z); pk[7] = f2b((gb).w);                                  \
    *reinterpret_cast<u16x8*>(reinterpret_cast<char*>(&(buf)[0]) + wbyte) = pk;\
  }

#define COMPUTE_KC(kc, cur)                                                    \
  {                                                                            \
    _Pragma("unroll")                                                          \
    for (int ks = 0; ks < 2; ks++) {                                           \
      bf16x8 a[4], bfr[4];                                                     \
      _Pragma("unroll")                                                        \
      for (int cg = 0; cg < 4; cg++) {                                         \
        int mr = cg * 16 + lr;                                                 \
        int rb = (ks * 64 + lk * 16) ^ ((mr & 7) << 4);                        \
        bfr[cg] = *reinterpret_cast<const bf16x8*>(                            \
            reinterpret_cast<const char*>(&smB[cur][0]) + mr * 128 + rb);      \
      }                                                                        \
      _Pragma("unroll")                                                        \
      for (int rg = 0; rg < 4; rg++)                                           \
        a[rg] = ldb8(vb + (size_t)(c0 + rg * 16 + lr) * NN + (kc) * 64 +       \
                     ks * 32 + lk * 8);                                        \
      _Pragma("unroll")                                                        \
      for (int rg = 0; rg < 4; rg++)                                           \
        _Pragma("unroll")                                                      \
        for (int cg = 0; cg < 4; cg++)                                         \
          acc[rg][cg] = MFMA16(a[rg], bfr[cg], acc[rg][cg]);                   \
    }                                                                          \
  }

#define SYNC_NODRAIN()                                   \
  asm volatile("s_waitcnt lgkmcnt(0)" ::: "memory");     \
  __builtin_amdgcn_s_barrier();                          \
  __builtin_amdgcn_sched_barrier(0);

  // prologue: loads for kc=0..3 in flight; stage kc=0
  f32x4v gqa[4], gqb[4];
#pragma unroll
  for (int d = 0; d < 4; d++) {
    gqa[d] = ntl4(attb + d * 64);
    gqb[d] = ntl4(attb + d * 64 + 4);
  }
  STAGE_WR(smB[0], gqa[0], gqb[0]);
  __syncthreads();

  f32x4 acc[4][4] = {};
  // main: kc = 0..59 (prefetch kc+4 <= 63, write kc+1 <= 60 always in range)
  for (int kc4 = 0; kc4 < 60; kc4 += 4) {
#pragma unroll
    for (int u = 0; u < 4; u++) {
      int kc = kc4 + u;
      gqa[u] = ntl4(attb + (kc + 4) * 64);          // issue load kc+4 (reuse slot)
      gqb[u] = ntl4(attb + (kc + 4) * 64 + 4);
      COMPUTE_KC(kc, (u & 1));
      STAGE_WR(smB[(u & 1) ^ 1], gqa[(u + 1) & 3], gqb[(u + 1) & 3]);  // kc+1 -> idle buf
      SYNC_NODRAIN();
    }
  }
  // tail: kc = 60..63, no prefetch
#pragma unroll
  for (int u = 0; u < 4; u++) {
    int kc = 60 + u;
    COMPUTE_KC(kc, (u & 1));
    if (u < 3) {
      STAGE_WR(smB[(u & 1) ^ 1], gqa[(u + 1) & 3], gqb[(u + 1) & 3]);
      SYNC_NODRAIN();
    }
  }
#undef STAGE_WR
#undef COMPUTE_KC
#undef SYNC_NODRAIN

  float gm = gamma[0];
  const float* xb = x + (size_t)b * CC * NN;
  float* ob = out + (size_t)b * CC * NN;
#pragma unroll
  for (int rg = 0; rg < 4; rg++)
#pragma unroll
    for (int i = 0; i < 4; i++) {
      int row = c0 + rg * 16 + lk * 4 + i;
#pragma unroll
      for (int cg = 0; cg < 4; cg++) {
        int col = m0 + cg * 16 + lr;
        size_t off = (size_t)row * NN + col;
        float xv = __builtin_nontemporal_load(&xb[off]);
        __builtin_nontemporal_store(gm * acc[rg][cg][i] + xv, &ob[off]);
      }
    }
}

extern "C" void kernel_launch(void* const* d_in, const int* in_sizes, int n_in,
                              void* d_out, int out_size, void* d_ws, size_t ws_size,
                              hipStream_t stream) {
  const float* x  = (const float*)d_in[0];
  const float* y  = (const float*)d_in[1];
  const float* wq = (const float*)d_in[2];
  const float* bq = (const float*)d_in[3];
  const float* wk = (const float*)d_in[4];
  const float* bk = (const float*)d_in[5];
  const float* wv = (const float*)d_in[6];
  const float* bv = (const float*)d_in[7];
  const float* gamma = (const float*)d_in[8];

  float* out = (float*)d_out;
  float* att = out + (size_t)BB * CC * NN;   // attention region of d_out

  // workspace layout (bytes)
  char* ws = (char*)d_ws;
  unsigned short* yT  = (unsigned short*)(ws);                 // 16 MiB  [B][N][C] bf16
  unsigned short* xT  = (unsigned short*)(ws + 16777216);      // 16 MiB
  unsigned short* q   = (unsigned short*)(ws + 33554432);      // 2 MiB   [B*N][64]
  unsigned short* kt  = (unsigned short*)(ws + 35651584);      // 2 MiB   [B*N][64]
  unsigned short* v   = (unsigned short*)(ws + 37748736);      // 16 MiB  [B][C][N]
  unsigned short* wqb = (unsigned short*)(ws + 54525952);      // 64 KiB
  unsigned short* wkb = (unsigned short*)(ws + 54591488);      // 64 KiB
  unsigned short* wvb = (unsigned short*)(ws + 54657024);      // 512 KiB
  if (ws_size < 55181312u) return;  // insufficient scratch -> fail loudly

  k_cvt_w<<<1280, 256, 0, stream>>>(wq, wk, wv, wqb, wkb, wvb);
  k_transpose<<<dim3(64, 8, 4), 256, 0, stream>>>(y, yT);
  k_transpose<<<dim3(64, 8, 4), 256, 0, stream>>>(x, xT);
  k_proj64<<<256, 256, 0, stream>>>(yT, wqb, bq, q, 1.44269504088896f);  // q pre-scaled by log2(e)
  k_proj64<<<256, 256, 0, stream>>>(yT, wkb, bk, kt, 1.0f);
  k_projv<<<dim3(16, 8, 4), 256, 0, stream>>>(wvb, xT, bv, v);
  k_att<<<dim3(128, 4), 512, 0, stream>>>(q, kt, att);
  k_pv<<<256, 512, 0, stream>>>(v, att, x, gamma, out);
}

// Round 7
// 377.369 us; speedup vs baseline: 1.9087x; 1.0048x over previous
//
#include <hip/hip_runtime.h>

// SelfAttn (SAGAN block): B=4, C=512, N=4096, C8=64
// out = gamma * (V @ softmax(Q K^T)^T) + x ; also outputs attention [B,N,N].
// All GEMMs via v_mfma_f32_16x16x32_bf16; fp32 accumulate.

#define BB 4
#define CC 512
#define NN 4096
#define C8V 64

typedef __bf16 bf16x8 __attribute__((ext_vector_type(8)));
typedef float f32x4 __attribute__((ext_vector_type(4)));
typedef float f32x4v __attribute__((ext_vector_type(4)));   // for nontemporal builtins
typedef unsigned short u16x8 __attribute__((ext_vector_type(8)));

#if __has_builtin(__builtin_amdgcn_exp2f)
#define EXP2(x) __builtin_amdgcn_exp2f(x)
#else
#define EXP2(x) exp2f(x)
#endif

#define MFMA16(a, b, c) __builtin_amdgcn_mfma_f32_16x16x32_bf16((a), (b), (c), 0, 0, 0)

__device__ __forceinline__ unsigned short f2b(float f) {
  union { float f; unsigned u; } x; x.f = f;
  unsigned u = x.u;
  u += 0x7fffu + ((u >> 16) & 1u);   // RNE round to bf16
  return (unsigned short)(u >> 16);
}

__device__ __forceinline__ bf16x8 ldb8(const unsigned short* p) {
  return *reinterpret_cast<const bf16x8*>(p);
}

__device__ __forceinline__ f32x4v ntl4(const float* p) {
  return __builtin_nontemporal_load(reinterpret_cast<const f32x4v*>(p));
}

// ---------------- weights fp32 -> bf16 ----------------
__global__ __launch_bounds__(256) void k_cvt_w(
    const float* __restrict__ wq, const float* __restrict__ wk, const float* __restrict__ wv,
    unsigned short* __restrict__ wqb, unsigned short* __restrict__ wkb, unsigned short* __restrict__ wvb) {
  int i = blockIdx.x * 256 + threadIdx.x;
  if (i < 32768)        wqb[i] = f2b(wq[i]);
  else if (i < 65536)   wkb[i - 32768] = f2b(wk[i - 32768]);
  else if (i < 327680)  wvb[i - 65536] = f2b(wv[i - 65536]);
}

// ---------------- transpose [C][N] f32 -> [N][C] bf16 (per batch) ----------------
__global__ __launch_bounds__(256) void k_transpose(const float* __restrict__ src,
                                                   unsigned short* __restrict__ dst) {
  __shared__ float tile[64][65];
  int b = blockIdx.z, c0 = blockIdx.y * 64, n0 = blockIdx.x * 64;
  const float* s = src + (size_t)b * CC * NN;
  unsigned short* d = dst + (size_t)b * NN * CC;
  int t = threadIdx.x;
#pragma unroll
  for (int j = 0; j < 4; j++) {
    int idx = t + j * 256, row = idx >> 4, col4 = (idx & 15) * 4;
    f32x4v v4 = *reinterpret_cast<const f32x4v*>(&s[(size_t)(c0 + row) * NN + n0 + col4]);
    tile[row][col4 + 0] = v4.x; tile[row][col4 + 1] = v4.y;
    tile[row][col4 + 2] = v4.z; tile[row][col4 + 3] = v4.w;
  }
  __syncthreads();
#pragma unroll
  for (int j = 0; j < 4; j++) {
    int idx = t + j * 256, nrow = idx >> 4, c4 = (idx & 15) * 4;
    ushort4 o;
    o.x = f2b(tile[c4 + 0][nrow]); o.y = f2b(tile[c4 + 1][nrow]);
    o.z = f2b(tile[c4 + 2][nrow]); o.w = f2b(tile[c4 + 3][nrow]);
    *reinterpret_cast<ushort4*>(&d[(size_t)(n0 + nrow) * CC + c0 + c4]) = o;
  }
}

// ---------------- Q/K projection: [M=16384][512] x [64][512]^T -> [M][64] bf16 ----------------
__global__ __launch_bounds__(256) void k_proj64(const unsigned short* __restrict__ aT,
                                                const unsigned short* __restrict__ wb,
                                                const float* __restrict__ bias,
                                                unsigned short* __restrict__ out, float scale) {
  int wave = threadIdx.x >> 6, l = threadIdx.x & 63;
  int r0 = blockIdx.x * 64 + wave * 16;
  int lr = l & 15, lk = l >> 4;
  const unsigned short* arow = aT + (size_t)(r0 + lr) * CC + lk * 8;
  f32x4 acc[4] = {};
  for (int ks = 0; ks < 16; ks++) {
    bf16x8 a = ldb8(arow + ks * 32);
#pragma unroll
    for (int cg = 0; cg < 4; cg++) {
      bf16x8 bfr = ldb8(wb + (size_t)(cg * 16 + lr) * CC + ks * 32 + lk * 8);
      acc[cg] = MFMA16(a, bfr, acc[cg]);
    }
  }
#pragma unroll
  for (int cg = 0; cg < 4; cg++) {
    int o = cg * 16 + lr;
    float bv = bias[o];
#pragma unroll
    for (int i = 0; i < 4; i++) {
      int row = r0 + lk * 4 + i;
      out[(size_t)row * C8V + o] = f2b((acc[cg][i] + bv) * scale);
    }
  }
}

// ---------------- V projection: wv[512][512] x xT[b][N][512] -> v[b][512][N] bf16 ----------------
__global__ __launch_bounds__(256) void k_projv(const unsigned short* __restrict__ wvb,
                                               const unsigned short* __restrict__ xT,
                                               const float* __restrict__ bv,
                                               unsigned short* __restrict__ v) {
  int b = blockIdx.z, c0 = blockIdx.y * 64;
  int wave = threadIdx.x >> 6, l = threadIdx.x & 63;
  int n0 = blockIdx.x * 256 + wave * 64;
  int lr = l & 15, lk = l >> 4;
  const unsigned short* xb = xT + (size_t)b * NN * CC;
  f32x4 acc[4][4] = {};
  for (int ks = 0; ks < 16; ks++) {
    bf16x8 a[4], bfr[4];
#pragma unroll
    for (int rg = 0; rg < 4; rg++)
      a[rg] = ldb8(wvb + (size_t)(c0 + rg * 16 + lr) * CC + ks * 32 + lk * 8);
#pragma unroll
    for (int cg = 0; cg < 4; cg++)
      bfr[cg] = ldb8(xb + (size_t)(n0 + cg * 16 + lr) * CC + ks * 32 + lk * 8);
#pragma unroll
    for (int rg = 0; rg < 4; rg++)
#pragma unroll
      for (int cg = 0; cg < 4; cg++)
        acc[rg][cg] = MFMA16(a[rg], bfr[cg], acc[rg][cg]);
  }
  unsigned short* vb = v + (size_t)b * CC * NN;
#pragma unroll
  for (int rg = 0; rg < 4; rg++)
#pragma unroll
    for (int i = 0; i < 4; i++) {
      int row = c0 + rg * 16 + lk * 4 + i;
      float bias = bv[row];
#pragma unroll
      for (int cg = 0; cg < 4; cg++) {
        int col = n0 + cg * 16 + lr;
        vb[(size_t)row * NN + col] = f2b(acc[rg][cg][i] + bias);
      }
    }
}

// ---------------- fused energy + softmax -> attention fp32 ----------------
// q pre-scaled by log2(e); softmax is shift-invariant, energies O(+-15),
// so no max subtraction needed. 512-thr blocks: 2 row-groups (16 rows each)
// x 4 column-quarters -> 4 waves/SIMD for latency hiding. Partial row sums
// combined across the 4 column waves via LDS.
__global__ __launch_bounds__(512) void k_att(const unsigned short* __restrict__ q,
                                             const unsigned short* __restrict__ kt,
                                             float* __restrict__ att) {
  __shared__ float psum[8][16];
  int b = blockIdx.y;
  int w = threadIdx.x >> 6, l = threadIdx.x & 63;
  int rg = w >> 2, cq = w & 3;
  int r0 = blockIdx.x * 32 + rg * 16;
  int lr = l & 15, lk = l >> 4;
  const unsigned short* qp = q + (size_t)(b * NN + r0 + lr) * C8V + lk * 8;
  bf16x8 aq0 = ldb8(qp);
  bf16x8 aq1 = ldb8(qp + 32);
  const unsigned short* ktb = kt + (size_t)b * NN * C8V;
  int jt0 = cq * 16;

  float lsum[4] = {0.f, 0.f, 0.f, 0.f};
  for (int jt = jt0; jt < jt0 + 16; jt++) {               // pass 1: partial row sums
    f32x4 acc[4] = {};
#pragma unroll
    for (int cg = 0; cg < 4; cg++) {
      const unsigned short* kp = ktb + (size_t)(jt * 64 + cg * 16 + lr) * C8V + lk * 8;
      acc[cg] = MFMA16(aq0, ldb8(kp), acc[cg]);
      acc[cg] = MFMA16(aq1, ldb8(kp + 32), acc[cg]);
    }
#pragma unroll
    for (int i = 0; i < 4; i++)
      lsum[i] += (EXP2(acc[0][i]) + EXP2(acc[1][i])) + (EXP2(acc[2][i]) + EXP2(acc[3][i]));
  }
#pragma unroll
  for (int i = 0; i < 4; i++) {
#pragma unroll
    for (int mm = 1; mm < 16; mm <<= 1) lsum[i] += __shfl_xor(lsum[i], mm);
  }
  if (lr == 0) {
#pragma unroll
    for (int i = 0; i < 4; i++) psum[w][lk * 4 + i] = lsum[i];
  }
  __syncthreads();
  float inv[4];
#pragma unroll
  for (int i = 0; i < 4; i++) {
    int rr = lk * 4 + i;
    inv[i] = 1.0f / (psum[rg * 4 + 0][rr] + psum[rg * 4 + 1][rr] +
                     psum[rg * 4 + 2][rr] + psum[rg * 4 + 3][rr]);
  }

  float* ab = att + (size_t)b * NN * NN;
  for (int jt = jt0; jt < jt0 + 16; jt++) {               // pass 2: write normalized
    f32x4 acc[4] = {};
#pragma unroll
    for (int cg = 0; cg < 4; cg++) {
      const unsigned short* kp = ktb + (size_t)(jt * 64 + cg * 16 + lr) * C8V + lk * 8;
      acc[cg] = MFMA16(aq0, ldb8(kp), acc[cg]);
      acc[cg] = MFMA16(aq1, ldb8(kp + 32), acc[cg]);
    }
#pragma unroll
    for (int cg = 0; cg < 4; cg++) {
      int col = jt * 64 + cg * 16 + lr;
#pragma unroll
      for (int i = 0; i < 4; i++) {
        int row = r0 + lk * 4 + i;
        __builtin_nontemporal_store(EXP2(acc[cg][i]) * inv[i], &ab[(size_t)row * NN + col]);
      }
    }
  }
}

// ---------------- PV + epilogue: out = gamma * (v @ att^T) + x ----------------
// Tile 64m x 512c, grid 256 (1 block/CU), XCD-pinned. att staged via depth-4
// register prefetch -> LDS double buffer (XOR-swizzled). Key fix (vmcnt FIFO):
// per kc the VMEM issue order is [ds_reads + v-loads] [att kc+4] pinned by
// sched_barrier(0), so MFMA waits are vmcnt(2) (never drain the in-flight att
// HBM loads), and STAGE's wait for att kc+1 (vmcnt(6)) was issued 4 kc ago.
// Barrier is raw s_barrier + lgkmcnt(0) only - no vmcnt drain.
__global__ __launch_bounds__(512, 2) void k_pv(const unsigned short* __restrict__ v,
                                               const float* __restrict__ att,
                                               const float* __restrict__ x,
                                               const float* __restrict__ gamma,
                                               float* __restrict__ out) {
  __shared__ unsigned short smB[2][64 * 64];   // 2 x 8 KiB
  int bid = blockIdx.x;
  int b = (bid & 7) >> 1;                       // XCD id = bid % 8 (round-robin)
  int m0 = ((bid >> 3) * 2 + (bid & 1)) * 64;   // 64 m-tiles per batch
  int t = threadIdx.x, wave = t >> 6, l = t & 63, lr = l & 15, lk = l >> 4;
  int c0 = wave * 64;
  int mrow = t >> 3, col8 = t & 7;              // staging: 64 rows x 8 f32x8
  const float* attb = att + ((size_t)b * NN + m0 + mrow) * NN + col8 * 8;
  const unsigned short* vb = v + (size_t)b * CC * NN;
  int wbyte = mrow * 128 + ((col8 * 16) ^ ((mrow & 7) << 4));  // swizzled write (bytes)

#define STAGE_WR(buf, ga, gb)                                                  \
  {                                                                            \
    u16x8 pk;                                                                  \
    pk[0] = f2b((ga).x); pk[1] = f2b((ga).y); pk[2] = f2b((ga).z);             \
    pk[3] = f2b((ga).w); pk[4] = f2b((gb).x); pk[5] = f2b((gb).y);             \
    pk[6] = f2b((gb).z); pk[7] = f2b((gb).w);                                  \
    *reinterpret_cast<u16x8*>(reinterpret_cast<char*>(&(buf)[0]) + wbyte) = pk;\
  }

// region 1: ALL loads for this kc (8 ds_read_b128 + 16 v global loads)
#define LOADS_KC(kc, cur)                                                      \
  _Pragma("unroll")                                                            \
  for (int cg = 0; cg < 4; cg++) {                                             \
    int mr = cg * 16 + lr;                                                     \
    int rb0 = (lk * 16) ^ ((mr & 7) << 4);                                     \
    int rb1 = (64 + lk * 16) ^ ((mr & 7) << 4);                                \
    const char* base = reinterpret_cast<const char*>(&smB[cur][0]) + mr * 128; \
    bf0[cg] = *reinterpret_cast<const bf16x8*>(base + rb0);                    \
    bf1[cg] = *reinterpret_cast<const bf16x8*>(base + rb1);                    \
  }                                                                            \
  _Pragma("unroll")                                                            \
  for (int rg = 0; rg < 4; rg++) {                                             \
    const unsigned short* vp = vb + (size_t)(c0 + rg * 16 + lr) * NN +         \
                               (kc) * 64 + lk * 8;                             \
    a0[rg] = ldb8(vp);                                                         \
    a1[rg] = ldb8(vp + 32);                                                    \
  }

// region 3: 32 MFMAs (vmcnt waits never exceed the att pair)
#define MFMAS_KC()                                                             \
  _Pragma("unroll")                                                            \
  for (int rg = 0; rg < 4; rg++)                                               \
    _Pragma("unroll")                                                          \
    for (int cg = 0; cg < 4; cg++)                                             \
      acc[rg][cg] = MFMA16(a0[rg], bf0[cg], acc[rg][cg]);                      \
  _Pragma("unroll")                                                            \
  for (int rg = 0; rg < 4; rg++)                                               \
    _Pragma("unroll")                                                          \
    for (int cg = 0; cg < 4; cg++)                                             \
      acc[rg][cg] = MFMA16(a1[rg], bf1[cg], acc[rg][cg]);

#define SYNC_NODRAIN()                                   \
  asm volatile("s_waitcnt lgkmcnt(0)" ::: "memory");     \
  __builtin_amdgcn_s_barrier();                          \
  __builtin_amdgcn_sched_barrier(0);

  // prologue: loads for kc=0..3 in flight; stage kc=0
  f32x4v gqa[4], gqb[4];
#pragma unroll
  for (int d = 0; d < 4; d++) {
    gqa[d] = ntl4(attb + d * 64);
    gqb[d] = ntl4(attb + d * 64 + 4);
  }
  STAGE_WR(smB[0], gqa[0], gqb[0]);
  __syncthreads();

  f32x4 acc[4][4] = {};
  bf16x8 a0[4], a1[4], bf0[4], bf1[4];
  // main: kc = 0..59 (prefetch kc+4 <= 63, stage kc+1 <= 60 always in range)
  for (int kc4 = 0; kc4 < 60; kc4 += 4) {
#pragma unroll
    for (int u = 0; u < 4; u++) {
      int kc = kc4 + u;
      LOADS_KC(kc, (u & 1));
      __builtin_amdgcn_sched_barrier(0);
      gqa[u] = ntl4(attb + (kc + 4) * 64);          // newest VMEM: att kc+4
      gqb[u] = ntl4(attb + (kc + 4) * 64 + 4);
      __builtin_amdgcn_sched_barrier(0);
      MFMAS_KC();
      STAGE_WR(smB[(u & 1) ^ 1], gqa[(u + 1) & 3], gqb[(u + 1) & 3]);  // kc+1 -> idle buf
      SYNC_NODRAIN();
    }
  }
  // tail: kc = 60..63, no prefetch
#pragma unroll
  for (int u = 0; u < 4; u++) {
    int kc = 60 + u;
    LOADS_KC(kc, (u & 1));
    MFMAS_KC();
    if (u < 3) {
      STAGE_WR(smB[(u & 1) ^ 1], gqa[(u + 1) & 3], gqb[(u + 1) & 3]);
      SYNC_NODRAIN();
    }
  }
#undef STAGE_WR
#undef LOADS_KC
#undef MFMAS_KC
#undef SYNC_NODRAIN

  float gm = gamma[0];
  const float* xb = x + (size_t)b * CC * NN;
  float* ob = out + (size_t)b * CC * NN;
#pragma unroll
  for (int rg = 0; rg < 4; rg++)
#pragma unroll
    for (int i = 0; i < 4; i++) {
      int row = c0 + rg * 16 + lk * 4 + i;
#pragma unroll
      for (int cg = 0; cg < 4; cg++) {
        int col = m0 + cg * 16 + lr;
        size_t off = (size_t)row * NN + col;
        float xv = __builtin_nontemporal_load(&xb[off]);
        __builtin_nontemporal_store(gm * acc[rg][cg][i] + xv, &ob[off]);
      }
    }
}

extern "C" void kernel_launch(void* const* d_in, const int* in_sizes, int n_in,
                              void* d_out, int out_size, void* d_ws, size_t ws_size,
                              hipStream_t stream) {
  const float* x  = (const float*)d_in[0];
  const float* y  = (const float*)d_in[1];
  const float* wq = (const float*)d_in[2];
  const float* bq = (const float*)d_in[3];
  const float* wk = (const float*)d_in[4];
  const float* bk = (const float*)d_in[5];
  const float* wv = (const float*)d_in[6];
  const float* bv = (const float*)d_in[7];
  const float* gamma = (const float*)d_in[8];

  float* out = (float*)d_out;
  float* att = out + (size_t)BB * CC * NN;   // attention region of d_out

  // workspace layout (bytes)
  char* ws = (char*)d_ws;
  unsigned short* yT  = (unsigned short*)(ws);                 // 16 MiB  [B][N][C] bf16
  unsigned short* xT  = (unsigned short*)(ws + 16777216);      // 16 MiB
  unsigned short* q   = (unsigned short*)(ws + 33554432);      // 2 MiB   [B*N][64]
  unsigned short* kt  = (unsigned short*)(ws + 35651584);      // 2 MiB   [B*N][64]
  unsigned short* v   = (unsigned short*)(ws + 37748736);      // 16 MiB  [B][C][N]
  unsigned short* wqb = (unsigned short*)(ws + 54525952);      // 64 KiB
  unsigned short* wkb = (unsigned short*)(ws + 54591488);      // 64 KiB
  unsigned short* wvb = (unsigned short*)(ws + 54657024);      // 512 KiB
  if (ws_size < 55181312u) return;  // insufficient scratch -> fail loudly

  k_cvt_w<<<1280, 256, 0, stream>>>(wq, wk, wv, wqb, wkb, wvb);
  k_transpose<<<dim3(64, 8, 4), 256, 0, stream>>>(y, yT);
  k_transpose<<<dim3(64, 8, 4), 256, 0, stream>>>(x, xT);
  k_proj64<<<256, 256, 0, stream>>>(yT, wqb, bq, q, 1.44269504088896f);  // q pre-scaled by log2(e)
  k_proj64<<<256, 256, 0, stream>>>(yT, wkb, bk, kt, 1.0f);
  k_projv<<<dim3(16, 8, 4), 256, 0, stream>>>(wvb, xT, bv, v);
  k_att<<<dim3(128, 4), 512, 0, stream>>>(q, kt, att);
  k_pv<<<256, 512, 0, stream>>>(v, att, x, gamma, out);
}

// Round 8
// 375.227 us; speedup vs baseline: 1.9196x; 1.0057x over previous
//
#include <hip/hip_runtime.h>

// SelfAttn (SAGAN block): B=4, C=512, N=4096, C8=64
// out = gamma * (V @ softmax(Q K^T)^T) + x ; also outputs attention [B,N,N].
// All GEMMs via v_mfma_f32_16x16x32_bf16; fp32 accumulate.
// R8: energy+softmax+att-write+PV fused in one kernel (att read-back eliminated).

#define BB 4
#define CC 512
#define NN 4096
#define C8V 64

typedef __bf16 bf16x8 __attribute__((ext_vector_type(8)));
typedef float f32x4 __attribute__((ext_vector_type(4)));
typedef float f32x4v __attribute__((ext_vector_type(4)));   // for nontemporal builtins
typedef unsigned short u16x8 __attribute__((ext_vector_type(8)));

#if __has_builtin(__builtin_amdgcn_exp2f)
#define EXP2(x) __builtin_amdgcn_exp2f(x)
#else
#define EXP2(x) exp2f(x)
#endif

#define MFMA16(a, b, c) __builtin_amdgcn_mfma_f32_16x16x32_bf16((a), (b), (c), 0, 0, 0)

__device__ __forceinline__ unsigned short f2b(float f) {
  union { float f; unsigned u; } x; x.f = f;
  unsigned u = x.u;
  u += 0x7fffu + ((u >> 16) & 1u);   // RNE round to bf16
  return (unsigned short)(u >> 16);
}

__device__ __forceinline__ bf16x8 ldb8(const unsigned short* p) {
  return *reinterpret_cast<const bf16x8*>(p);
}

__device__ __forceinline__ f32x4v ntl4(const float* p) {
  return __builtin_nontemporal_load(reinterpret_cast<const f32x4v*>(p));
}

// ---------------- weights fp32 -> bf16 ----------------
__global__ __launch_bounds__(256) void k_cvt_w(
    const float* __restrict__ wq, const float* __restrict__ wk, const float* __restrict__ wv,
    unsigned short* __restrict__ wqb, unsigned short* __restrict__ wkb, unsigned short* __restrict__ wvb) {
  int i = blockIdx.x * 256 + threadIdx.x;
  if (i < 32768)        wqb[i] = f2b(wq[i]);
  else if (i < 65536)   wkb[i - 32768] = f2b(wk[i - 32768]);
  else if (i < 327680)  wvb[i - 65536] = f2b(wv[i - 65536]);
}

// ---------------- transpose [C][N] f32 -> [N][C] bf16 (per batch) ----------------
__global__ __launch_bounds__(256) void k_transpose(const float* __restrict__ src,
                                                   unsigned short* __restrict__ dst) {
  __shared__ float tile[64][65];
  int b = blockIdx.z, c0 = blockIdx.y * 64, n0 = blockIdx.x * 64;
  const float* s = src + (size_t)b * CC * NN;
  unsigned short* d = dst + (size_t)b * NN * CC;
  int t = threadIdx.x;
#pragma unroll
  for (int j = 0; j < 4; j++) {
    int idx = t + j * 256, row = idx >> 4, col4 = (idx & 15) * 4;
    f32x4v v4 = *reinterpret_cast<const f32x4v*>(&s[(size_t)(c0 + row) * NN + n0 + col4]);
    tile[row][col4 + 0] = v4.x; tile[row][col4 + 1] = v4.y;
    tile[row][col4 + 2] = v4.z; tile[row][col4 + 3] = v4.w;
  }
  __syncthreads();
#pragma unroll
  for (int j = 0; j < 4; j++) {
    int idx = t + j * 256, nrow = idx >> 4, c4 = (idx & 15) * 4;
    ushort4 o;
    o.x = f2b(tile[c4 + 0][nrow]); o.y = f2b(tile[c4 + 1][nrow]);
    o.z = f2b(tile[c4 + 2][nrow]); o.w = f2b(tile[c4 + 3][nrow]);
    *reinterpret_cast<ushort4*>(&d[(size_t)(n0 + nrow) * CC + c0 + c4]) = o;
  }
}

// ---------------- Q/K projection: [M=16384][512] x [64][512]^T -> [M][64] bf16 ----------------
__global__ __launch_bounds__(256) void k_proj64(const unsigned short* __restrict__ aT,
                                                const unsigned short* __restrict__ wb,
                                                const float* __restrict__ bias,
                                                unsigned short* __restrict__ out, float scale) {
  int wave = threadIdx.x >> 6, l = threadIdx.x & 63;
  int r0 = blockIdx.x * 64 + wave * 16;
  int lr = l & 15, lk = l >> 4;
  const unsigned short* arow = aT + (size_t)(r0 + lr) * CC + lk * 8;
  f32x4 acc[4] = {};
  for (int ks = 0; ks < 16; ks++) {
    bf16x8 a = ldb8(arow + ks * 32);
#pragma unroll
    for (int cg = 0; cg < 4; cg++) {
      bf16x8 bfr = ldb8(wb + (size_t)(cg * 16 + lr) * CC + ks * 32 + lk * 8);
      acc[cg] = MFMA16(a, bfr, acc[cg]);
    }
  }
#pragma unroll
  for (int cg = 0; cg < 4; cg++) {
    int o = cg * 16 + lr;
    float bv = bias[o];
#pragma unroll
    for (int i = 0; i < 4; i++) {
      int row = r0 + lk * 4 + i;
      out[(size_t)row * C8V + o] = f2b((acc[cg][i] + bv) * scale);
    }
  }
}

// ---------------- V projection: wv[512][512] x xT[b][N][512] -> v[b][512][N] bf16 ----------------
__global__ __launch_bounds__(256) void k_projv(const unsigned short* __restrict__ wvb,
                                               const unsigned short* __restrict__ xT,
                                               const float* __restrict__ bv,
                                               unsigned short* __restrict__ v) {
  int b = blockIdx.z, c0 = blockIdx.y * 64;
  int wave = threadIdx.x >> 6, l = threadIdx.x & 63;
  int n0 = blockIdx.x * 256 + wave * 64;
  int lr = l & 15, lk = l >> 4;
  const unsigned short* xb = xT + (size_t)b * NN * CC;
  f32x4 acc[4][4] = {};
  for (int ks = 0; ks < 16; ks++) {
    bf16x8 a[4], bfr[4];
#pragma unroll
    for (int rg = 0; rg < 4; rg++)
      a[rg] = ldb8(wvb + (size_t)(c0 + rg * 16 + lr) * CC + ks * 32 + lk * 8);
#pragma unroll
    for (int cg = 0; cg < 4; cg++)
      bfr[cg] = ldb8(xb + (size_t)(n0 + cg * 16 + lr) * CC + ks * 32 + lk * 8);
#pragma unroll
    for (int rg = 0; rg < 4; rg++)
#pragma unroll
      for (int cg = 0; cg < 4; cg++)
        acc[rg][cg] = MFMA16(a[rg], bfr[cg], acc[rg][cg]);
  }
  unsigned short* vb = v + (size_t)b * CC * NN;
#pragma unroll
  for (int rg = 0; rg < 4; rg++)
#pragma unroll
    for (int i = 0; i < 4; i++) {
      int row = c0 + rg * 16 + lk * 4 + i;
      float bias = bv[row];
#pragma unroll
      for (int cg = 0; cg < 4; cg++) {
        int col = n0 + cg * 16 + lr;
        vb[(size_t)row * NN + col] = f2b(acc[rg][cg][i] + bias);
      }
    }
}

// ---------------- fused: energy + softmax + att write + PV + epilogue ----------------
// Grid 256 (1 block/CU), XCD-pinned: batch b on XCDs {2b,2b+1} -> v[b], kt[b],
// q[b] L2-resident. Block = 64 q-rows (m0..m0+63), 8 waves.
// Pass 1: row sums of exp2(energy) (q pre-scaled by log2(e); no max needed,
//   energies O(+-15)). Wave w: rows rg=w>>1, col-half nh=w&1 of each chunk.
// Pass 2 per 64-col chunk jt: QK^T (4 MFMA/wave) -> p = exp2*inv ->
//   att[m][n] written straight from regs (nontemporal, 268 MB = the floor);
//   p packed bf16 -> swizzled LDS P[2][64][64] (double buffer);
//   ONE lgkmcnt-only barrier; PV: out[c][m] += v[c,n-chunk] @ P^T
//   (A = v rows from L2, B = P rows from LDS, 32 MFMA/wave).
// Att re-read from HBM is eliminated entirely (was 268 MB + a latency-bound
// kernel); pass 2 is write-paced so MFMA and v-L2 traffic hide under it.
__global__ __launch_bounds__(512) void k_fused(const unsigned short* __restrict__ q,
                                               const unsigned short* __restrict__ kt,
                                               const unsigned short* __restrict__ v,
                                               const float* __restrict__ x,
                                               const float* __restrict__ gamma,
                                               float* __restrict__ out,
                                               float* __restrict__ att) {
  __shared__ unsigned short smP[2][64 * 64];   // 2 x 8 KiB bf16 P tiles
  __shared__ float psum[8][16];

  int bid = blockIdx.x;
  int b = (bid & 7) >> 1;                       // XCD id = bid % 8
  int m0 = ((bid >> 3) * 2 + (bid & 1)) * 64;   // 64 m-tiles per batch
  int t = threadIdx.x, w = t >> 6, l = t & 63, lr = l & 15, lk = l >> 4;
  int rg = w >> 1, nh = w & 1;                  // QK^T: rows rg*16.., col-half nh
  int c0w = w * 64;                             // PV: c-rows per wave

  const unsigned short* ktb = kt + (size_t)b * NN * C8V;
  const unsigned short* vb = v + (size_t)b * CC * NN;
  float* ab = att + (size_t)b * NN * NN;

  // Q fragments for rows m0 + rg*16 + lr (K = 64 in two halves)
  const unsigned short* qp = q + (size_t)(b * NN + m0 + rg * 16 + lr) * C8V + lk * 8;
  bf16x8 aq0 = ldb8(qp), aq1 = ldb8(qp + 32);

  // ---- pass 1: row sums over this wave's col-half of every chunk ----
  float lsum[4] = {0.f, 0.f, 0.f, 0.f};
  for (int jt = 0; jt < 64; jt++) {
    f32x4 acc2[2] = {};
#pragma unroll
    for (int cg = 0; cg < 2; cg++) {
      const unsigned short* kp = ktb + (size_t)(jt * 64 + nh * 32 + cg * 16 + lr) * C8V + lk * 8;
      acc2[cg] = MFMA16(aq0, ldb8(kp), acc2[cg]);
      acc2[cg] = MFMA16(aq1, ldb8(kp + 32), acc2[cg]);
    }
#pragma unroll
    for (int i = 0; i < 4; i++)
      lsum[i] += EXP2(acc2[0][i]) + EXP2(acc2[1][i]);
  }
#pragma unroll
  for (int i = 0; i < 4; i++) {
#pragma unroll
    for (int mm = 1; mm < 16; mm <<= 1) lsum[i] += __shfl_xor(lsum[i], mm);
  }
  if (lr == 0) {
#pragma unroll
    for (int i = 0; i < 4; i++) psum[w][lk * 4 + i] = lsum[i];
  }
  __syncthreads();
  float inv[4];
#pragma unroll
  for (int i = 0; i < 4; i++)
    inv[i] = 1.0f / (psum[rg * 2][lk * 4 + i] + psum[rg * 2 + 1][lk * 4 + i]);

  // ---- pass 2: recompute -> att write + P(LDS) -> PV accumulate ----
  f32x4 acc[4][4] = {};   // out tile [64c x 64m] per wave
  for (int jt = 0; jt < 64; jt++) {
    int cur = jt & 1;
    f32x4 acc2[2] = {};
#pragma unroll
    for (int cg = 0; cg < 2; cg++) {
      const unsigned short* kp = ktb + (size_t)(jt * 64 + nh * 32 + cg * 16 + lr) * C8V + lk * 8;
      acc2[cg] = MFMA16(aq0, ldb8(kp), acc2[cg]);
      acc2[cg] = MFMA16(aq1, ldb8(kp + 32), acc2[cg]);
    }
    char* pbuf = reinterpret_cast<char*>(&smP[cur][0]);
#pragma unroll
    for (int cg = 0; cg < 2; cg++) {
      int nl = nh * 32 + cg * 16 + lr;
#pragma unroll
      for (int i = 0; i < 4; i++) {
        int ml = rg * 16 + lk * 4 + i;
        float p = EXP2(acc2[cg][i]) * inv[i];
        __builtin_nontemporal_store(p, &ab[(size_t)(m0 + ml) * NN + jt * 64 + nl]);
        *reinterpret_cast<unsigned short*>(pbuf + ml * 128 + ((nl * 2) ^ ((ml & 7) << 4))) = f2b(p);
      }
    }
    asm volatile("s_waitcnt lgkmcnt(0)" ::: "memory");
    __builtin_amdgcn_s_barrier();
    __builtin_amdgcn_sched_barrier(0);
    const char* pr = reinterpret_cast<const char*>(&smP[cur][0]);
#pragma unroll
    for (int ks = 0; ks < 2; ks++) {
      bf16x8 a[4], bfr[4];
#pragma unroll
      for (int cg = 0; cg < 4; cg++) {
        int mr = cg * 16 + lr;
        bfr[cg] = *reinterpret_cast<const bf16x8*>(pr + mr * 128 + ((ks * 64 + lk * 16) ^ ((mr & 7) << 4)));
      }
#pragma unroll
      for (int rg2 = 0; rg2 < 4; rg2++)
        a[rg2] = ldb8(vb + (size_t)(c0w + rg2 * 16 + lr) * NN + jt * 64 + ks * 32 + lk * 8);
#pragma unroll
      for (int rg2 = 0; rg2 < 4; rg2++)
#pragma unroll
        for (int cg = 0; cg < 4; cg++)
          acc[rg2][cg] = MFMA16(a[rg2], bfr[cg], acc[rg2][cg]);
    }
  }

  // ---- epilogue: out = gamma*acc + x ----
  float gm = gamma[0];
  const float* xb = x + (size_t)b * CC * NN;
  float* ob = out + (size_t)b * CC * NN;
#pragma unroll
  for (int rg2 = 0; rg2 < 4; rg2++)
#pragma unroll
    for (int i = 0; i < 4; i++) {
      int row = c0w + rg2 * 16 + lk * 4 + i;
#pragma unroll
      for (int cg = 0; cg < 4; cg++) {
        int col = m0 + cg * 16 + lr;
        size_t off = (size_t)row * NN + col;
        float xv = __builtin_nontemporal_load(&xb[off]);
        __builtin_nontemporal_store(gm * acc[rg2][cg][i] + xv, &ob[off]);
      }
    }
}

extern "C" void kernel_launch(void* const* d_in, const int* in_sizes, int n_in,
                              void* d_out, int out_size, void* d_ws, size_t ws_size,
                              hipStream_t stream) {
  const float* x  = (const float*)d_in[0];
  const float* y  = (const float*)d_in[1];
  const float* wq = (const float*)d_in[2];
  const float* bq = (const float*)d_in[3];
  const float* wk = (const float*)d_in[4];
  const float* bk = (const float*)d_in[5];
  const float* wv = (const float*)d_in[6];
  const float* bv = (const float*)d_in[7];
  const float* gamma = (const float*)d_in[8];

  float* out = (float*)d_out;
  float* att = out + (size_t)BB * CC * NN;   // attention region of d_out

  // workspace layout (bytes)
  char* ws = (char*)d_ws;
  unsigned short* yT  = (unsigned short*)(ws);                 // 16 MiB  [B][N][C] bf16
  unsigned short* xT  = (unsigned short*)(ws + 16777216);      // 16 MiB
  unsigned short* q   = (unsigned short*)(ws + 33554432);      // 2 MiB   [B*N][64]
  unsigned short* kt  = (unsigned short*)(ws + 35651584);      // 2 MiB   [B*N][64]
  unsigned short* v   = (unsigned short*)(ws + 37748736);      // 16 MiB  [B][C][N]
  unsigned short* wqb = (unsigned short*)(ws + 54525952);      // 64 KiB
  unsigned short* wkb = (unsigned short*)(ws + 54591488);      // 64 KiB
  unsigned short* wvb = (unsigned short*)(ws + 54657024);      // 512 KiB
  if (ws_size < 55181312u) return;  // insufficient scratch -> fail loudly

  k_cvt_w<<<1280, 256, 0, stream>>>(wq, wk, wv, wqb, wkb, wvb);
  k_transpose<<<dim3(64, 8, 4), 256, 0, stream>>>(y, yT);
  k_transpose<<<dim3(64, 8, 4), 256, 0, stream>>>(x, xT);
  k_proj64<<<256, 256, 0, stream>>>(yT, wqb, bq, q, 1.44269504088896f);  // q pre-scaled by log2(e)
  k_proj64<<<256, 256, 0, stream>>>(yT, wkb, bk, kt, 1.0f);
  k_projv<<<dim3(16, 8, 4), 256, 0, stream>>>(wvb, xT, bv, v);
  k_fused<<<256, 512, 0, stream>>>(q, kt, v, x, gamma, out, att);
}

// Round 9
// 342.744 us; speedup vs baseline: 2.1015x; 1.0948x over previous
//
#include <hip/hip_runtime.h>

// SelfAttn (SAGAN block): B=4, C=512, N=4096, C8=64
// out = gamma * (V @ softmax(Q K^T)^T) + x ; also outputs attention [B,N,N].
// All GEMMs via v_mfma_f32_16x16x32_bf16; fp32 accumulate.
// R9: fused kernel pass 2 fully software-pipelined (kt/v/QK^T one iter ahead).

#define BB 4
#define CC 512
#define NN 4096
#define C8V 64

typedef __bf16 bf16x8 __attribute__((ext_vector_type(8)));
typedef float f32x4 __attribute__((ext_vector_type(4)));
typedef float f32x4v __attribute__((ext_vector_type(4)));   // for nontemporal builtins
typedef unsigned short u16x8 __attribute__((ext_vector_type(8)));

#if __has_builtin(__builtin_amdgcn_exp2f)
#define EXP2(x) __builtin_amdgcn_exp2f(x)
#else
#define EXP2(x) exp2f(x)
#endif

#define MFMA16(a, b, c) __builtin_amdgcn_mfma_f32_16x16x32_bf16((a), (b), (c), 0, 0, 0)

__device__ __forceinline__ unsigned short f2b(float f) {
  union { float f; unsigned u; } x; x.f = f;
  unsigned u = x.u;
  u += 0x7fffu + ((u >> 16) & 1u);   // RNE round to bf16
  return (unsigned short)(u >> 16);
}

__device__ __forceinline__ bf16x8 ldb8(const unsigned short* p) {
  return *reinterpret_cast<const bf16x8*>(p);
}

// ---------------- weights fp32 -> bf16 ----------------
__global__ __launch_bounds__(256) void k_cvt_w(
    const float* __restrict__ wq, const float* __restrict__ wk, const float* __restrict__ wv,
    unsigned short* __restrict__ wqb, unsigned short* __restrict__ wkb, unsigned short* __restrict__ wvb) {
  int i = blockIdx.x * 256 + threadIdx.x;
  if (i < 32768)        wqb[i] = f2b(wq[i]);
  else if (i < 65536)   wkb[i - 32768] = f2b(wk[i - 32768]);
  else if (i < 327680)  wvb[i - 65536] = f2b(wv[i - 65536]);
}

// ---------------- transpose [C][N] f32 -> [N][C] bf16 (per batch) ----------------
__global__ __launch_bounds__(256) void k_transpose(const float* __restrict__ src,
                                                   unsigned short* __restrict__ dst) {
  __shared__ float tile[64][65];
  int b = blockIdx.z, c0 = blockIdx.y * 64, n0 = blockIdx.x * 64;
  const float* s = src + (size_t)b * CC * NN;
  unsigned short* d = dst + (size_t)b * NN * CC;
  int t = threadIdx.x;
#pragma unroll
  for (int j = 0; j < 4; j++) {
    int idx = t + j * 256, row = idx >> 4, col4 = (idx & 15) * 4;
    f32x4v v4 = *reinterpret_cast<const f32x4v*>(&s[(size_t)(c0 + row) * NN + n0 + col4]);
    tile[row][col4 + 0] = v4.x; tile[row][col4 + 1] = v4.y;
    tile[row][col4 + 2] = v4.z; tile[row][col4 + 3] = v4.w;
  }
  __syncthreads();
#pragma unroll
  for (int j = 0; j < 4; j++) {
    int idx = t + j * 256, nrow = idx >> 4, c4 = (idx & 15) * 4;
    ushort4 o;
    o.x = f2b(tile[c4 + 0][nrow]); o.y = f2b(tile[c4 + 1][nrow]);
    o.z = f2b(tile[c4 + 2][nrow]); o.w = f2b(tile[c4 + 3][nrow]);
    *reinterpret_cast<ushort4*>(&d[(size_t)(n0 + nrow) * CC + c0 + c4]) = o;
  }
}

// ---------------- Q/K projection: [M=16384][512] x [64][512]^T -> [M][64] bf16 ----------------
__global__ __launch_bounds__(256) void k_proj64(const unsigned short* __restrict__ aT,
                                                const unsigned short* __restrict__ wb,
                                                const float* __restrict__ bias,
                                                unsigned short* __restrict__ out, float scale) {
  int wave = threadIdx.x >> 6, l = threadIdx.x & 63;
  int r0 = blockIdx.x * 64 + wave * 16;
  int lr = l & 15, lk = l >> 4;
  const unsigned short* arow = aT + (size_t)(r0 + lr) * CC + lk * 8;
  f32x4 acc[4] = {};
  for (int ks = 0; ks < 16; ks++) {
    bf16x8 a = ldb8(arow + ks * 32);
#pragma unroll
    for (int cg = 0; cg < 4; cg++) {
      bf16x8 bfr = ldb8(wb + (size_t)(cg * 16 + lr) * CC + ks * 32 + lk * 8);
      acc[cg] = MFMA16(a, bfr, acc[cg]);
    }
  }
#pragma unroll
  for (int cg = 0; cg < 4; cg++) {
    int o = cg * 16 + lr;
    float bv = bias[o];
#pragma unroll
    for (int i = 0; i < 4; i++) {
      int row = r0 + lk * 4 + i;
      out[(size_t)row * C8V + o] = f2b((acc[cg][i] + bv) * scale);
    }
  }
}

// ---------------- V projection: wv[512][512] x xT[b][N][512] -> v[b][512][N] bf16 ----------------
__global__ __launch_bounds__(256) void k_projv(const unsigned short* __restrict__ wvb,
                                               const unsigned short* __restrict__ xT,
                                               const float* __restrict__ bv,
                                               unsigned short* __restrict__ v) {
  int b = blockIdx.z, c0 = blockIdx.y * 64;
  int wave = threadIdx.x >> 6, l = threadIdx.x & 63;
  int n0 = blockIdx.x * 256 + wave * 64;
  int lr = l & 15, lk = l >> 4;
  const unsigned short* xb = xT + (size_t)b * NN * CC;
  f32x4 acc[4][4] = {};
  for (int ks = 0; ks < 16; ks++) {
    bf16x8 a[4], bfr[4];
#pragma unroll
    for (int rg = 0; rg < 4; rg++)
      a[rg] = ldb8(wvb + (size_t)(c0 + rg * 16 + lr) * CC + ks * 32 + lk * 8);
#pragma unroll
    for (int cg = 0; cg < 4; cg++)
      bfr[cg] = ldb8(xb + (size_t)(n0 + cg * 16 + lr) * CC + ks * 32 + lk * 8);
#pragma unroll
    for (int rg = 0; rg < 4; rg++)
#pragma unroll
      for (int cg = 0; cg < 4; cg++)
        acc[rg][cg] = MFMA16(a[rg], bfr[cg], acc[rg][cg]);
  }
  unsigned short* vb = v + (size_t)b * CC * NN;
#pragma unroll
  for (int rg = 0; rg < 4; rg++)
#pragma unroll
    for (int i = 0; i < 4; i++) {
      int row = c0 + rg * 16 + lk * 4 + i;
      float bias = bv[row];
#pragma unroll
      for (int cg = 0; cg < 4; cg++) {
        int col = n0 + cg * 16 + lr;
        vb[(size_t)row * NN + col] = f2b(acc[rg][cg][i] + bias);
      }
    }
}

// ---------------- fused: energy + softmax + att write + PV + epilogue ----------------
// Grid 256 (1 block/CU), XCD-pinned. Pass 2 is software-pipelined one
// iteration deep for EVERY operand: at iteration jt,
//   - softmax/att-store/P-LDS uses QK^T computed at jt-1 (register data),
//   - QK^T for jt+1 runs on kt regs loaded at jt-1 (pure-register MFMA),
//   - v regs for PV(jt) were loaded at jt-1,
//   - loads issued this iter: v[jt+1], kt[jt+2].
// Barrier = lgkmcnt(0) + raw s_barrier (no vmcnt drain), so global loads
// stay in flight across it. Only same-phase latency is the LDS P read,
// hidden under the 32 PV MFMAs.
__global__ __launch_bounds__(512, 2) void k_fused(const unsigned short* __restrict__ q,
                                                  const unsigned short* __restrict__ kt,
                                                  const unsigned short* __restrict__ v,
                                                  const float* __restrict__ x,
                                                  const float* __restrict__ gamma,
                                                  float* __restrict__ out,
                                                  float* __restrict__ att) {
  __shared__ unsigned short smP[2][64 * 64];   // 2 x 8 KiB bf16 P tiles
  __shared__ float psum[8][16];

  int bid = blockIdx.x;
  int b = (bid & 7) >> 1;                       // XCD id = bid % 8
  int m0 = ((bid >> 3) * 2 + (bid & 1)) * 64;   // 64 m-tiles per batch
  int t = threadIdx.x, w = t >> 6, l = t & 63, lr = l & 15, lk = l >> 4;
  int rg = w >> 1, nh = w & 1;                  // QK^T: rows rg*16.., col-half nh
  int c0w = w * 64;                             // PV: c-rows per wave

  const unsigned short* ktb = kt + (size_t)b * NN * C8V;
  const unsigned short* vb = v + (size_t)b * CC * NN;
  float* ab = att + (size_t)b * NN * NN;

  const unsigned short* qp = q + (size_t)(b * NN + m0 + rg * 16 + lr) * C8V + lk * 8;
  bf16x8 aq0 = ldb8(qp), aq1 = ldb8(qp + 32);

  // ---- pass 1: row sums (no barriers; compiler pipelines freely) ----
  float lsum[4] = {0.f, 0.f, 0.f, 0.f};
  for (int jt = 0; jt < 64; jt++) {
    f32x4 acc2[2] = {};
#pragma unroll
    for (int cg = 0; cg < 2; cg++) {
      const unsigned short* kp = ktb + (size_t)(jt * 64 + nh * 32 + cg * 16 + lr) * C8V + lk * 8;
      acc2[cg] = MFMA16(aq0, ldb8(kp), acc2[cg]);
      acc2[cg] = MFMA16(aq1, ldb8(kp + 32), acc2[cg]);
    }
#pragma unroll
    for (int i = 0; i < 4; i++)
      lsum[i] += EXP2(acc2[0][i]) + EXP2(acc2[1][i]);
  }
#pragma unroll
  for (int i = 0; i < 4; i++) {
#pragma unroll
    for (int mm = 1; mm < 16; mm <<= 1) lsum[i] += __shfl_xor(lsum[i], mm);
  }
  if (lr == 0) {
#pragma unroll
    for (int i = 0; i < 4; i++) psum[w][lk * 4 + i] = lsum[i];
  }
  __syncthreads();
  float inv[4];
#pragma unroll
  for (int i = 0; i < 4; i++)
    inv[i] = 1.0f / (psum[rg * 2][lk * 4 + i] + psum[rg * 2 + 1][lk * 4 + i]);

  // ---- pass 2: pipelined recompute -> att write + P(LDS) -> PV ----
#define LDKT(d0, d1, JT)                                                       \
  _Pragma("unroll")                                                            \
  for (int cg = 0; cg < 2; cg++) {                                             \
    const unsigned short* kp =                                                 \
        ktb + (size_t)((JT) * 64 + nh * 32 + cg * 16 + lr) * C8V + lk * 8;     \
    d0[cg] = ldb8(kp);                                                         \
    d1[cg] = ldb8(kp + 32);                                                    \
  }

#define QKT(dst, k0, k1)                                                       \
  _Pragma("unroll")                                                            \
  for (int cg = 0; cg < 2; cg++) {                                             \
    f32x4 z = {};                                                              \
    z = MFMA16(aq0, k0[cg], z);                                                \
    dst[cg] = MFMA16(aq1, k1[cg], z);                                          \
  }

#define LDV(dst, JT)                                                           \
  _Pragma("unroll")                                                            \
  for (int rg2 = 0; rg2 < 4; rg2++) {                                          \
    const unsigned short* vp =                                                 \
        vb + (size_t)(c0w + rg2 * 16 + lr) * NN + (JT) * 64 + lk * 8;          \
    dst[rg2 * 2] = ldb8(vp);                                                   \
    dst[rg2 * 2 + 1] = ldb8(vp + 32);                                          \
  }

#define SMSTORE(qk, CUR, JT)                                                   \
  {                                                                            \
    char* pbuf = reinterpret_cast<char*>(&smP[CUR][0]);                        \
    _Pragma("unroll")                                                          \
    for (int cg = 0; cg < 2; cg++) {                                           \
      int nl = nh * 32 + cg * 16 + lr;                                         \
      _Pragma("unroll")                                                        \
      for (int i = 0; i < 4; i++) {                                            \
        int ml = rg * 16 + lk * 4 + i;                                         \
        float p = EXP2(qk[cg][i]) * inv[i];                                    \
        __builtin_nontemporal_store(p, &ab[(size_t)(m0 + ml) * NN + (JT) * 64 + nl]); \
        *reinterpret_cast<unsigned short*>(                                    \
            pbuf + ml * 128 + ((nl * 2) ^ ((ml & 7) << 4))) = f2b(p);          \
      }                                                                        \
    }                                                                          \
  }

#define PV(vsrc, CUR)                                                          \
  {                                                                            \
    const char* pr = reinterpret_cast<const char*>(&smP[CUR][0]);              \
    _Pragma("unroll")                                                          \
    for (int ks = 0; ks < 2; ks++) {                                           \
      bf16x8 bfr[4];                                                           \
      _Pragma("unroll")                                                        \
      for (int cg = 0; cg < 4; cg++) {                                         \
        int mr = cg * 16 + lr;                                                 \
        bfr[cg] = *reinterpret_cast<const bf16x8*>(                            \
            pr + mr * 128 + ((ks * 64 + lk * 16) ^ ((mr & 7) << 4)));          \
      }                                                                        \
      _Pragma("unroll")                                                        \
      for (int rg2 = 0; rg2 < 4; rg2++)                                        \
        _Pragma("unroll")                                                      \
        for (int cg = 0; cg < 4; cg++)                                         \
          acc[rg2][cg] = MFMA16(vsrc[rg2 * 2 + ks], bfr[cg], acc[rg2][cg]);    \
    }                                                                          \
  }

#define BODY(qkC, qkN, ktN0, ktN1, ktF0, ktF1, vC, vN, CUR, JT)                \
  {                                                                            \
    SMSTORE(qkC, CUR, JT);                                                     \
    LDV(vN, ((JT) + 1 > 63 ? 63 : (JT) + 1));                                  \
    QKT(qkN, ktN0, ktN1);                                                      \
    LDKT(ktF0, ktF1, ((JT) + 2 > 63 ? 63 : (JT) + 2));                         \
    asm volatile("s_waitcnt lgkmcnt(0)" ::: "memory");                         \
    __builtin_amdgcn_s_barrier();                                              \
    __builtin_amdgcn_sched_barrier(0);                                         \
    PV(vC, CUR);                                                               \
  }

  f32x4 acc[4][4] = {};
  f32x4 qkA[2], qkB[2];
  bf16x8 ktA0[2], ktA1[2], ktB0[2], ktB1[2];
  bf16x8 vA[8], vB[8];

  // prologue: qkA = QK^T(0); ktA = kt[1]; vA = v[0]
  LDKT(ktB0, ktB1, 0);
  QKT(qkA, ktB0, ktB1);
  LDKT(ktA0, ktA1, 1);
  LDV(vA, 0);

  for (int jt = 0; jt < 64; jt += 2) {
    BODY(qkA, qkB, ktA0, ktA1, ktB0, ktB1, vA, vB, 0, jt);
    BODY(qkB, qkA, ktB0, ktB1, ktA0, ktA1, vB, vA, 1, jt + 1);
  }
#undef LDKT
#undef QKT
#undef LDV
#undef SMSTORE
#undef PV
#undef BODY

  // ---- epilogue: out = gamma*acc + x ----
  float gm = gamma[0];
  const float* xb = x + (size_t)b * CC * NN;
  float* ob = out + (size_t)b * CC * NN;
#pragma unroll
  for (int rg2 = 0; rg2 < 4; rg2++)
#pragma unroll
    for (int i = 0; i < 4; i++) {
      int row = c0w + rg2 * 16 + lk * 4 + i;
#pragma unroll
      for (int cg = 0; cg < 4; cg++) {
        int col = m0 + cg * 16 + lr;
        size_t off = (size_t)row * NN + col;
        float xv = __builtin_nontemporal_load(&xb[off]);
        __builtin_nontemporal_store(gm * acc[rg2][cg][i] + xv, &ob[off]);
      }
    }
}

extern "C" void kernel_launch(void* const* d_in, const int* in_sizes, int n_in,
                              void* d_out, int out_size, void* d_ws, size_t ws_size,
                              hipStream_t stream) {
  const float* x  = (const float*)d_in[0];
  const float* y  = (const float*)d_in[1];
  const float* wq = (const float*)d_in[2];
  const float* bq = (const float*)d_in[3];
  const float* wk = (const float*)d_in[4];
  const float* bk = (const float*)d_in[5];
  const float* wv = (const float*)d_in[6];
  const float* bv = (const float*)d_in[7];
  const float* gamma = (const float*)d_in[8];

  float* out = (float*)d_out;
  float* att = out + (size_t)BB * CC * NN;   // attention region of d_out

  // workspace layout (bytes)
  char* ws = (char*)d_ws;
  unsigned short* yT  = (unsigned short*)(ws);                 // 16 MiB  [B][N][C] bf16
  unsigned short* xT  = (unsigned short*)(ws + 16777216);      // 16 MiB
  unsigned short* q   = (unsigned short*)(ws + 33554432);      // 2 MiB   [B*N][64]
  unsigned short* kt  = (unsigned short*)(ws + 35651584);      // 2 MiB   [B*N][64]
  unsigned short* v   = (unsigned short*)(ws + 37748736);      // 16 MiB  [B][C][N]
  unsigned short* wqb = (unsigned short*)(ws + 54525952);      // 64 KiB
  unsigned short* wkb = (unsigned short*)(ws + 54591488);      // 64 KiB
  unsigned short* wvb = (unsigned short*)(ws + 54657024);      // 512 KiB
  if (ws_size < 55181312u) return;  // insufficient scratch -> fail loudly

  k_cvt_w<<<1280, 256, 0, stream>>>(wq, wk, wv, wqb, wkb, wvb);
  k_transpose<<<dim3(64, 8, 4), 256, 0, stream>>>(y, yT);
  k_transpose<<<dim3(64, 8, 4), 256, 0, stream>>>(x, xT);
  k_proj64<<<256, 256, 0, stream>>>(yT, wqb, bq, q, 1.44269504088896f);  // q pre-scaled by log2(e)
  k_proj64<<<256, 256, 0, stream>>>(yT, wkb, bk, kt, 1.0f);
  k_projv<<<dim3(16, 8, 4), 256, 0, stream>>>(wvb, xT, bv, v);
  k_fused<<<256, 512, 0, stream>>>(q, kt, v, x, gamma, out, att);
}